// Round 7
// baseline (335.339 us; speedup 1.0000x reference)
//
#include <hip/hip_runtime.h>
#include <hip/hip_bf16.h>
#include <stdint.h>

// ---------------------------------------------------------------------------
// CausalSelfAttention: x(4,2048,1024) fp32 -> out fp32
// qkv = x@w_attn+b_attn; flash-attn causal (H=16,hd=64); out = attn@w_proj+b_proj
// R13: attn rewritten — Q-tile 256 rows, 4 waves, 64 q-rows/wave (4 groups).
//   Old design: every wave read the SAME Ks/Vs fragments (kf/vf addrs are
//   lane-only) -> 4x redundant LDS traffic, LDS-bound (~2300 cyc/CU-iter LDS
//   vs 1400 MFMA). Now each wave's kf/vf reads feed 4x the MFMA (groups
//   g=0..3 at rows qt*256+g*64+w*16+l15); block-iters 512x34 -> 256x36,
//   grid 4x64=256 = 1 block/CU. Uniform loop: group g active iff
//   kt <= 4qt+g (wave-uniform), diagonal mask (keyl > w*16+l15) at equality
//   — same mask algebra as the old half0/half1 + tail special-case, verified
//   by offset arithmetic. Staging ring / swizzles / exp2 / epilogue verbatim.
// gemm16q (R12, best of 6 structure variants: 71.5us QKV, 0 conflicts,
//   FETCH 41MB): quadrant phases, intrinsic barriers, counted vmcnt,
//   XCD A-panel mapping. QKV NF=4 grid 384; proj NF=2 grid 256.
// Workspace: xb 16MB (aliased by Vt after QKV GEMM) | wat 6MB | wpt 2MB |
//            qkv 48MB | attn 16MB  = 88 MB
// ---------------------------------------------------------------------------

typedef uint16_t u16;
typedef __bf16 bf16x8 __attribute__((ext_vector_type(8)));
typedef __bf16 bf16x4 __attribute__((ext_vector_type(4)));
typedef short s16x4 __attribute__((ext_vector_type(4)));
typedef float f32x4 __attribute__((ext_vector_type(4)));

#define S_LEN 2048
#define DMODEL 1024
#define NHEAD 16
#define HDIM 64
#define MTOT 8192   // B*S
#define NQKV 3072

__device__ __forceinline__ u16 f2bf(float f) {
    union { float f; uint32_t u; } v; v.f = f;
    uint32_t u = v.u;
    return (u16)((u + 0x7fffu + ((u >> 16) & 1u)) >> 16);  // RNE
}

__device__ __forceinline__ s16x4 bits4(bf16x4 v) {
    union { bf16x4 b; s16x4 s; } u; u.b = v; return u.s;
}

// D = A*B + C, 16x16x16 bf16 (A,B: 4 bf16/lane, k = q4*4+j)
__device__ __forceinline__ f32x4 mfma16(bf16x4 a, bf16x4 b, f32x4 c) {
    return __builtin_amdgcn_mfma_f32_16x16x16bf16_1k(bits4(a), bits4(b), c, 0, 0, 0);
}

__device__ __forceinline__ void async_load16(const void* g, void* l) {
    __builtin_amdgcn_global_load_lds(
        (__attribute__((address_space(1))) void*)g,
        (__attribute__((address_space(3))) void*)l,
        16, 0, 0);
}

// ---- prep: fp32 -> bf16 (vectorized) --------------------------------------
__global__ void convert_x_kernel(const float4* __restrict__ in, ushort4* __restrict__ out, int n4) {
    int i = blockIdx.x * 256 + threadIdx.x;
    if (i < n4) {
        float4 f = in[i];
        ushort4 o;
        o.x = f2bf(f.x); o.y = f2bf(f.y); o.z = f2bf(f.z); o.w = f2bf(f.w);
        out[i] = o;
    }
}

// ---- prep: transpose + convert: in (R x C) fp32 -> out (C x R) bf16 --------
__global__ void transpose_bf16_kernel(const float* __restrict__ in, u16* __restrict__ out, int R, int C) {
    __shared__ float tile[64][65];
    int r0 = blockIdx.y * 64, c0 = blockIdx.x * 64;
    #pragma unroll
    for (int i = 0; i < 16; ++i) {
        int idx = threadIdx.x + i * 256;
        int r = idx >> 6, c = idx & 63;
        tile[r][c] = in[(size_t)(r0 + r) * C + c0 + c];
    }
    __syncthreads();
    #pragma unroll
    for (int i = 0; i < 16; ++i) {
        int idx = threadIdx.x + i * 256;
        int c = idx >> 6, r = idx & 63;
        out[(size_t)(c0 + c) * R + r0 + r] = f2bf(tile[r][c]);
    }
}

// ---- V transpose: qkv V-section (token-major) -> Vt[bh][d][s] --------------
__global__ void transpose_v_kernel(const u16* __restrict__ qkv, u16* __restrict__ vt) {
    __shared__ u16 tile[64 * 66];
    const int tid = threadIdx.x;
    const int stile = blockIdx.x, bh = blockIdx.y;
    const int b = bh >> 4, h = bh & 15;
    const u16* src = qkv + ((size_t)b * S_LEN + stile * 64) * NQKV + 2 * DMODEL + h * HDIM;
    #pragma unroll
    for (int it = 0; it < 2; ++it) {
        int item = it * 256 + tid;
        int s = item >> 3, d0 = (item & 7) * 8;
        bf16x8 v = *(const bf16x8*)(src + (size_t)s * NQKV + d0);
        const u16* vu = (const u16*)&v;
        #pragma unroll
        for (int j = 0; j < 8; ++j) tile[(d0 + j) * 66 + s] = vu[j];
    }
    __syncthreads();
    #pragma unroll
    for (int it = 0; it < 2; ++it) {
        int item = it * 256 + tid;
        int d = item >> 3, s0 = (item & 7) * 8;
        union { u16 u[8]; uint4 v; } pk;
        #pragma unroll
        for (int j = 0; j < 8; ++j) pk.u[j] = tile[d * 66 + s0 + j];
        *(uint4*)(vt + ((size_t)bh * 64 + d) * S_LEN + stile * 64 + s0) = pk.v;
    }
}

// ---- GEMM16Q: C[M,N] = A[M,K] @ Bt[N,K]^T + bias, quadrant phases ----------
// (R12 — best measured GEMM structure this session.)
template<int NF, bool OUT_BF16>
__global__ __launch_bounds__(512, 2) void gemm16q(
    const u16* __restrict__ A, const u16* __restrict__ Bt,
    const float* __restrict__ bias, void* __restrict__ C,
    int M, int N, int K)
{
    constexpr int NBH = NF / 2;            // B half-tiles (128 rows) per K-tile
    constexpr int BSLOT = NF * 4096;       // u16 per B parity buffer (BN x 64)
    __shared__ __attribute__((aligned(16))) u16 sm[32768 + 2 * BSLOT];
    u16* const As = sm;                    // 4 x 8192 u16: slot (par*2+half)
    u16* const Bs = sm + 32768;            // 2 x BSLOT u16: slot par

    const int tid = threadIdx.x;
    const int wave = tid >> 6, lane = tid & 63;
    const int l15 = lane & 15, q4 = lane >> 4;
    const int wm = wave >> 2, wn = wave & 3;

    // XCD-resident A-panel mapping
    const int bid = (int)blockIdx.x;
    const int xcd = bid & 7;
    const int lx  = bid >> 3;
    const int MB  = M >> 8;                // 32
    const int PM  = MB >> 3;               // 4 rows per XCD panel
    const int nb  = lx / PM;
    const int mb  = xcd * PM + (lx - nb * PM);
    const int m0 = mb << 8, n0 = nb * NF * 64;

    const u16* Ag = A + (size_t)m0 * K;
    const u16* Bg = Bt + (size_t)n0 * K;

    const int srow = tid >> 3;
    const size_t goff0 = (size_t)srow * K + (size_t)(((tid & 7) ^ (srow & 7)) * 8);
    const size_t goff1 = goff0 + (size_t)64 * K;
    const int ldso = tid * 8;

    const int ck0 = (q4 ^ (l15 & 7)) * 8;
    const int ck1 = ((4 + q4) ^ (l15 & 7)) * 8;
    const int rb0 = (wn * NF * 16 + l15) * 64;   // B row base (nf=0)

    f32x4 acc[8][NF] = {};
    const int T = K >> 6;

#define STAGE_A(t_, h_) do { \
    const u16* ga_ = Ag + (size_t)(h_) * 128 * K + (size_t)(t_) * 64; \
    u16* da_ = As + (((t_) & 1) * 2 + (h_)) * 8192; \
    async_load16(ga_ + goff0, da_ + ldso); \
    async_load16(ga_ + goff1, da_ + ldso + 4096); \
} while (0)

#define STAGE_B(t_, h_) do { \
    const u16* gb_ = Bg + (size_t)(h_) * 128 * K + (size_t)(t_) * 64; \
    u16* db_ = Bs + ((t_) & 1) * BSLOT + (h_) * 8192; \
    async_load16(gb_ + goff0, db_ + ldso); \
    async_load16(gb_ + goff1, db_ + ldso + 4096); \
} while (0)

#define LOAD_AF(P_) do { \
    af[0][0] = *(const bf16x8*)(Ah + ((2 * (P_)) * 16 + l15) * 64 + ck0); \
    af[0][1] = *(const bf16x8*)(Ah + ((2 * (P_)) * 16 + l15) * 64 + ck1); \
    af[1][0] = *(const bf16x8*)(Ah + ((2 * (P_) + 1) * 16 + l15) * 64 + ck0); \
    af[1][1] = *(const bf16x8*)(Ah + ((2 * (P_) + 1) * 16 + l15) * 64 + ck1); \
} while (0)

#define PHASE_MFMA(P_) do { \
    __builtin_amdgcn_s_barrier(); \
    __builtin_amdgcn_s_setprio(1); \
    _Pragma("unroll") \
    for (int i_ = 0; i_ < 2; ++i_) \
        _Pragma("unroll") \
        for (int nf_ = 0; nf_ < NF; ++nf_) \
            _Pragma("unroll") \
            for (int kk_ = 0; kk_ < 2; ++kk_) \
                acc[2 * (P_) + i_][nf_] = __builtin_amdgcn_mfma_f32_16x16x32_bf16( \
                    af[i_][kk_], bfr[nf_][kk_], acc[2 * (P_) + i_][nf_], 0, 0, 0); \
    __builtin_amdgcn_s_setprio(0); \
} while (0)

    // prologue: A(0) both halves + B(0) + B(1); keep B(1) in flight
    STAGE_A(0, 0); STAGE_A(0, 1);
    STAGE_B(0, 0); if constexpr (NBH == 2) STAGE_B(0, 1);
    if (T > 1) {
        STAGE_B(1, 0); if constexpr (NBH == 2) STAGE_B(1, 1);
        if constexpr (NBH == 2) asm volatile("s_waitcnt vmcnt(4)");
        else                    asm volatile("s_waitcnt vmcnt(2)");
    } else {
        asm volatile("s_waitcnt vmcnt(0)");
    }
    __builtin_amdgcn_sched_barrier(0);
    __builtin_amdgcn_s_barrier();

    for (int t = 0; t < T; ++t) {
        const int par = t & 1;
        const u16* Ah = As + (par * 2 + wm) * 8192;   // this wave's A half
        const u16* Bl = Bs + par * BSLOT;

        bf16x8 af[2][2], bfr[NF][2];

        // ---- phase 0: ALL bfr (held all tile) + af m-frags 0,1 -------------
        #pragma unroll
        for (int nf = 0; nf < NF; ++nf) {
            bfr[nf][0] = *(const bf16x8*)(Bl + rb0 + nf * (16 * 64) + ck0);
            bfr[nf][1] = *(const bf16x8*)(Bl + rb0 + nf * (16 * 64) + ck1);
        }
        LOAD_AF(0);
        if (t + 1 < T) STAGE_A(t + 1, 0);
        PHASE_MFMA(0);
        __builtin_amdgcn_s_barrier();

        // ---- phase 1: af m-frags 2,3; stage A(t+1).h1 ----------------------
        LOAD_AF(1);
        if (t + 1 < T) STAGE_A(t + 1, 1);
        PHASE_MFMA(1);
        __builtin_amdgcn_s_barrier();

        // ---- phase 2: af m-frags 4,5; stage B(t+2).h0 into B[par] ----------
        LOAD_AF(2);
        if (t + 2 < T) STAGE_B(t + 2, 0);
        PHASE_MFMA(2);
        __builtin_amdgcn_s_barrier();

        // ---- phase 3: af m-frags 6,7; stage B(t+2).h1 ----------------------
        LOAD_AF(3);
        if constexpr (NBH == 2) { if (t + 2 < T) STAGE_B(t + 2, 1); }
        PHASE_MFMA(3);
        if (t + 1 < T) {
            if (t + 2 < T) {
                if constexpr (NBH == 2) asm volatile("s_waitcnt vmcnt(4)");
                else                    asm volatile("s_waitcnt vmcnt(2)");
            } else {
                asm volatile("s_waitcnt vmcnt(0)");
            }
            __builtin_amdgcn_sched_barrier(0);
            __builtin_amdgcn_s_barrier();
        }
    }

#undef STAGE_A
#undef STAGE_B
#undef LOAD_AF
#undef PHASE_MFMA

    // epilogue: C/D col=l15, row=q4*4+r
    #pragma unroll
    for (int mf = 0; mf < 8; ++mf) {
        const int row = m0 + wm * 128 + mf * 16 + q4 * 4;
        #pragma unroll
        for (int nf = 0; nf < NF; ++nf) {
            const int col = n0 + wn * NF * 16 + nf * 16 + l15;
            const float bv = bias[col];
            #pragma unroll
            for (int r = 0; r < 4; ++r) {
                float v = acc[mf][nf][r] + bv;
                if (OUT_BF16) ((u16*)C)[(size_t)(row + r) * N + col] = f2bf(v);
                else          ((float*)C)[(size_t)(row + r) * N + col] = v;
            }
        }
    }
}

// ---- flash attention R13 ---------------------------------------------------
// One Q-tile pass: 256 q-rows at tile qt; 4 waves, wave w owns rows
// qt*256 + g*64 + w*16 + l15 for groups g=0..3. Triple-buffered 64-key K/V
// ring with prefetch-2 (identical staging). Per kt: group g active iff
// kt <= 4qt+g; diagonal mask (keyl > w*16+l15) at equality.
__device__ __forceinline__ void stage_tiles(
    const u16* __restrict__ qkv, const u16* __restrict__ vt,
    size_t base, int bh, int h, int w, int srow8, int schunk,
    int kt, u16* __restrict__ KsB, u16* __restrict__ VsB)
{
    #pragma unroll
    for (int q = 0; q < 2; ++q) {
        int rloc = w * 16 + q * 8 + srow8;
        int sc = ((schunk ^ (rloc & 7)) * 8);
        async_load16(qkv + (base + (size_t)kt * 64 + rloc) * (size_t)NQKV + DMODEL + h * HDIM + sc,
                     KsB + (w * 16 + q * 8) * 64);
        async_load16(vt + ((size_t)bh * 64 + rloc) * S_LEN + kt * 64 + sc,
                     VsB + (w * 16 + q * 8) * 64);
    }
}

__device__ __forceinline__ void attn_pass(
    int qt, const u16* __restrict__ qkv, const u16* __restrict__ vt,
    __bf16* __restrict__ outb, u16 (*Ks)[64 * 64], u16 (*Vs)[64 * 64],
    int w, int lane, int bh, int h, size_t base)
{
    const int l15 = lane & 15, q4 = lane >> 4;
    const int srow8 = lane >> 3, schunk = lane & 7;

    // Q fragments for 4 groups ([n=q=l15][k=d=q4*8+j]); scale folds
    // 1/sqrt(64) * log2(e) so P = 2^(K·Q^T) == e^(K·Q^T/8).
    const float QSCALE = 0.125f * 1.44269504f;
    bf16x8 qf[4][2];
    #pragma unroll
    for (int g = 0; g < 4; ++g) {
        int qrow = qt * 256 + g * 64 + w * 16 + l15;
        #pragma unroll
        for (int kc = 0; kc < 2; ++kc) {
            bf16x8 raw = *(const bf16x8*)(qkv + (base + qrow) * (size_t)NQKV + h * HDIM + kc * 32 + q4 * 8);
            bf16x8 sc;
            #pragma unroll
            for (int j = 0; j < 8; ++j) sc[j] = (__bf16)((float)raw[j] * QSCALE);
            qf[g][kc] = sc;
        }
    }

    bf16x4 ones4;
    #pragma unroll
    for (int j = 0; j < 4; ++j) ones4[j] = (__bf16)1.0f;

    f32x4 o[4][4] = {};   // O^T per group: [g][d-tile mt][q=l15], rows d=q4*4+r
    f32x4 la[4] = {};     // l[g][q=l15]

    const int ktlast = 4 * qt + 3;  // >= 3 always

    __syncthreads();                // protect LDS reuse across passes
    stage_tiles(qkv, vt, base, bh, h, w, srow8, schunk, 0, Ks[0], Vs[0]);
    stage_tiles(qkv, vt, base, bh, h, w, srow8, schunk, 1, Ks[1], Vs[1]);

    for (int kt = 0; kt <= ktlast; ++kt) {
        const int buf = kt % 3;
        __syncthreads();            // kt,kt+1 staged; reads of buf (kt+2)%3 done
        int pf = kt + 2;
        if (pf <= ktlast)
            stage_tiles(qkv, vt, base, bh, h, w, srow8, schunk, pf, Ks[pf % 3], Vs[pf % 3]);

        // S^T = K·Q^T per active group; kf shared across groups
        f32x4 st[4][4] = {};
        #pragma unroll
        for (int nt = 0; nt < 4; ++nt) {
            int n = nt * 16 + l15;      // key row in Ks
            #pragma unroll
            for (int kc = 0; kc < 2; ++kc) {
                int ch = (((kc * 4 + q4) ^ (n & 7)) * 8);
                bf16x8 kf = *(const bf16x8*)(&Ks[buf][n * 64 + ch]);
                #pragma unroll
                for (int g = 0; g < 4; ++g)
                    if (kt <= 4 * qt + g)
                        st[g][nt] = __builtin_amdgcn_mfma_f32_16x16x32_bf16(
                            kf, qf[g][kc], st[g][nt], 0, 0, 0);
            }
        }

        // mask + P^T = 2^(S^T) packed to bf16x4 B-frags (k = q4*4+j)
        bf16x4 pb[4][4];
        #pragma unroll
        for (int g = 0; g < 4; ++g) {
            if (kt > 4 * qt + g) continue;           // fully masked group
            const bool diag = (kt == 4 * qt + g);    // wave-uniform
            #pragma unroll
            for (int nt = 0; nt < 4; ++nt)
                #pragma unroll
                for (int r = 0; r < 4; ++r) {
                    float s = st[g][nt][r];
                    if (diag) {
                        int keyl = nt * 16 + q4 * 4 + r;
                        if (keyl > w * 16 + l15) s = -1e30f;
                    }
                    pb[g][nt][r] = (__bf16)__builtin_amdgcn_exp2f(s);
                }
        }

        // O^T += V^T · P^T (vf shared across groups); l += ones · P^T
        #pragma unroll
        for (int nt = 0; nt < 4; ++nt) {
            #pragma unroll
            for (int mt = 0; mt < 4; ++mt) {
                int row = mt * 16 + l15;                       // d row in Vs
                int ch = (nt * 2 + (q4 >> 1)) ^ (row & 7);
                bf16x4 vf = *(const bf16x4*)(&Vs[buf][row * 64 + ch * 8 + (q4 & 1) * 4]);
                #pragma unroll
                for (int g = 0; g < 4; ++g)
                    if (kt <= 4 * qt + g)
                        o[g][mt] = mfma16(vf, pb[g][nt], o[g][mt]);
            }
            #pragma unroll
            for (int g = 0; g < 4; ++g)
                if (kt <= 4 * qt + g)
                    la[g] = mfma16(ones4, pb[g][nt], la[g]);
        }
    }

    // epilogue: lane holds O^T[d = mt*16+q4*4+r][q=l15]; packed 8B stores
    #pragma unroll
    for (int g = 0; g < 4; ++g) {
        float inv = 1.0f / la[g][0];
        int row = qt * 256 + g * 64 + w * 16 + l15;
        #pragma unroll
        for (int mt = 0; mt < 4; ++mt) {
            union { __bf16 b[4]; ushort4 v; } p;
            #pragma unroll
            for (int r = 0; r < 4; ++r)
                p.b[r] = (__bf16)(o[g][mt][r] * inv);
            int col = h * HDIM + mt * 16 + q4 * 4;
            *(ushort4*)(&outb[(base + row) * (size_t)DMODEL + col]) = p.v;
        }
    }
}

// block = (bx, bh): processes Q-tiles qt = NT-1-bx and qt = bx (36 K-iters
// total for every block -> perfect load balance). gridDim.x = NT/2 = 4.
__global__ __launch_bounds__(256, 1) void attn_kernel(
    const u16* __restrict__ qkv, const u16* __restrict__ vt, u16* __restrict__ out)
{
    __shared__ __attribute__((aligned(16))) u16 Ks[3][64 * 64];
    __shared__ __attribute__((aligned(16))) u16 Vs[3][64 * 64];

    const int tid = threadIdx.x;
    const int w = tid >> 6, lane = tid & 63;
    const int bh = blockIdx.y;
    const int b = bh >> 4, h = bh & 15;
    const size_t base = (size_t)b * S_LEN;
    const int NT = (int)gridDim.x * 2;           // 8 tiles of 256 rows

    attn_pass(NT - 1 - (int)blockIdx.x, qkv, vt, (__bf16*)out, Ks, Vs, w, lane, bh, h, base);
    attn_pass((int)blockIdx.x,          qkv, vt, (__bf16*)out, Ks, Vs, w, lane, bh, h, base);
}

extern "C" void kernel_launch(void* const* d_in, const int* in_sizes, int n_in,
                              void* d_out, int out_size, void* d_ws, size_t ws_size,
                              hipStream_t stream) {
    const float* x      = (const float*)d_in[0];
    // d_in[1] = mask (causal tril) — implemented structurally, not read
    const float* w_attn = (const float*)d_in[2];
    const float* b_attn = (const float*)d_in[3];
    const float* w_proj = (const float*)d_in[4];
    const float* b_proj = (const float*)d_in[5];

    u16* xb   = (u16*)d_ws;                                   // 8192x1024 (dead after QKV GEMM)
    u16* wat  = xb  + (size_t)MTOT * DMODEL;                  // 3072x1024
    u16* wpt  = wat + (size_t)NQKV * DMODEL;                  // 1024x1024
    u16* qkv  = wpt + (size_t)DMODEL * DMODEL;                // 8192x3072
    u16* attn = qkv + (size_t)MTOT * NQKV;                    // 8192x1024
    u16* vt   = xb;                                           // Vt[64 bh][64 d][2048 s] aliases xb

    convert_x_kernel<<<(MTOT * DMODEL / 4 + 255) / 256, 256, 0, stream>>>(
        (const float4*)x, (ushort4*)xb, MTOT * DMODEL / 4);
    transpose_bf16_kernel<<<dim3(NQKV / 64, DMODEL / 64), 256, 0, stream>>>(w_attn, wat, DMODEL, NQKV);
    transpose_bf16_kernel<<<dim3(DMODEL / 64, DMODEL / 64), 256, 0, stream>>>(w_proj, wpt, DMODEL, DMODEL);

    gemm16q<4, true><<<dim3((MTOT / 256) * (NQKV / 256)), 512, 0, stream>>>(
        xb, wat, b_attn, (void*)qkv, MTOT, NQKV, DMODEL);

    transpose_v_kernel<<<dim3(S_LEN / 64, 4 * NHEAD), 256, 0, stream>>>(qkv, vt);

    attn_kernel<<<dim3(S_LEN / 512, 4 * NHEAD), 256, 0, stream>>>(qkv, vt, attn);

    gemm16q<2, false><<<dim3((MTOT / 256) * (DMODEL / 128)), 512, 0, stream>>>(
        attn, wpt, b_proj, d_out, MTOT, DMODEL, DMODEL);
}

// Round 8
// 268.885 us; speedup vs baseline: 1.2471x; 1.2471x over previous
//
#include <hip/hip_runtime.h>
#include <hip/hip_bf16.h>
#include <stdint.h>

// ---------------------------------------------------------------------------
// CausalSelfAttention: x(4,2048,1024) fp32 -> out fp32
// qkv = x@w_attn+b_attn; flash-attn causal (H=16,hd=64); out = attn@w_proj+b_proj
// R14: (1) attn reverted to R6 (R13's 256-row/4-wave tile dropped occupancy
//   to 1 wave/SIMD -> latency-bound, 133us vs R6's ~68us). (2) The three
//   prep kernels (x->bf16 convert, w_attn transpose, w_proj transpose) are
//   merged into ONE range-dispatched kernel: launch count 7 -> 5. Budget
//   arithmetic (270 total vs ~230 kernel-sum) attributes ~60-70us to the
//   ~10us/launch overhead, so -2 launches ~= -20us.
// gemm16q (R12, best of 6 structure variants: 71.5us QKV, 0 conflicts,
//   FETCH 41MB): quadrant phases, intrinsic barriers, counted vmcnt,
//   XCD A-panel mapping. QKV NF=4 grid 384; proj NF=2 grid 256.
// attn (R6): paired Q-tiles (34 K-iters per block), triple-buffered K/V ring
//   prefetch-2, S^T=K.Q^T -> exp2 -> P^T in regs -> O^T=V^T.P^T.
// Workspace: xb 16MB (aliased by Vt after QKV GEMM) | wat 6MB | wpt 2MB |
//            qkv 48MB | attn 16MB  = 88 MB
// ---------------------------------------------------------------------------

typedef uint16_t u16;
typedef __bf16 bf16x8 __attribute__((ext_vector_type(8)));
typedef __bf16 bf16x4 __attribute__((ext_vector_type(4)));
typedef short s16x4 __attribute__((ext_vector_type(4)));
typedef float f32x4 __attribute__((ext_vector_type(4)));

#define S_LEN 2048
#define DMODEL 1024
#define NHEAD 16
#define HDIM 64
#define MTOT 8192   // B*S
#define NQKV 3072

__device__ __forceinline__ u16 f2bf(float f) {
    union { float f; uint32_t u; } v; v.f = f;
    uint32_t u = v.u;
    return (u16)((u + 0x7fffu + ((u >> 16) & 1u)) >> 16);  // RNE
}

__device__ __forceinline__ s16x4 bits4(bf16x4 v) {
    union { bf16x4 b; s16x4 s; } u; u.b = v; return u.s;
}

// D = A*B + C, 16x16x16 bf16 (A,B: 4 bf16/lane, k = q4*4+j)
__device__ __forceinline__ f32x4 mfma16(bf16x4 a, bf16x4 b, f32x4 c) {
    return __builtin_amdgcn_mfma_f32_16x16x16bf16_1k(bits4(a), bits4(b), c, 0, 0, 0);
}

__device__ __forceinline__ void async_load16(const void* g, void* l) {
    __builtin_amdgcn_global_load_lds(
        (__attribute__((address_space(1))) void*)g,
        (__attribute__((address_space(3))) void*)l,
        16, 0, 0);
}

// ---- merged prep: convert x -> bf16 | transpose w_attn | transpose w_proj --
// Range dispatch on blockIdx.x:
//   [0, NCONV)             : x fp32 -> bf16 (float4/ushort4 vectorized)
//   [NCONV, NCONV+NWAT)    : w_attn (1024x3072) -> wat (3072x1024) bf16
//   [NCONV+NWAT, +NWPT)    : w_proj (1024x1024) -> wpt (1024x1024) bf16
#define NCONV (MTOT * DMODEL / 4 / 256)            // 8192 blocks
#define NWAT  ((NQKV / 64) * (DMODEL / 64))        // 48*16 = 768
#define NWPT  ((DMODEL / 64) * (DMODEL / 64))      // 16*16 = 256

__device__ __forceinline__ void transpose_tile(
    const float* __restrict__ in, u16* __restrict__ out, int R, int C,
    int bx, int by, int tid)
{
    __shared__ float tile[64][65];
    int r0 = by * 64, c0 = bx * 64;
    #pragma unroll
    for (int i = 0; i < 16; ++i) {
        int idx = tid + i * 256;
        int r = idx >> 6, c = idx & 63;
        tile[r][c] = in[(size_t)(r0 + r) * C + c0 + c];
    }
    __syncthreads();
    #pragma unroll
    for (int i = 0; i < 16; ++i) {
        int idx = tid + i * 256;
        int c = idx >> 6, r = idx & 63;
        out[(size_t)(c0 + c) * R + r0 + r] = f2bf(tile[r][c]);
    }
}

__global__ void prep_kernel(
    const float4* __restrict__ x4, ushort4* __restrict__ xb4,
    const float* __restrict__ w_attn, u16* __restrict__ wat,
    const float* __restrict__ w_proj, u16* __restrict__ wpt)
{
    const int bid = blockIdx.x;
    const int tid = threadIdx.x;
    if (bid < NCONV) {
        int i = bid * 256 + tid;
        float4 f = x4[i];
        ushort4 o;
        o.x = f2bf(f.x); o.y = f2bf(f.y); o.z = f2bf(f.z); o.w = f2bf(f.w);
        xb4[i] = o;
    } else if (bid < NCONV + NWAT) {
        int b2 = bid - NCONV;
        transpose_tile(w_attn, wat, DMODEL, NQKV, b2 % (NQKV / 64), b2 / (NQKV / 64), tid);
    } else {
        int b3 = bid - NCONV - NWAT;
        transpose_tile(w_proj, wpt, DMODEL, DMODEL, b3 % (DMODEL / 64), b3 / (DMODEL / 64), tid);
    }
}

// ---- V transpose: qkv V-section (token-major) -> Vt[bh][d][s] --------------
__global__ void transpose_v_kernel(const u16* __restrict__ qkv, u16* __restrict__ vt) {
    __shared__ u16 tile[64 * 66];
    const int tid = threadIdx.x;
    const int stile = blockIdx.x, bh = blockIdx.y;
    const int b = bh >> 4, h = bh & 15;
    const u16* src = qkv + ((size_t)b * S_LEN + stile * 64) * NQKV + 2 * DMODEL + h * HDIM;
    #pragma unroll
    for (int it = 0; it < 2; ++it) {
        int item = it * 256 + tid;
        int s = item >> 3, d0 = (item & 7) * 8;
        bf16x8 v = *(const bf16x8*)(src + (size_t)s * NQKV + d0);
        const u16* vu = (const u16*)&v;
        #pragma unroll
        for (int j = 0; j < 8; ++j) tile[(d0 + j) * 66 + s] = vu[j];
    }
    __syncthreads();
    #pragma unroll
    for (int it = 0; it < 2; ++it) {
        int item = it * 256 + tid;
        int d = item >> 3, s0 = (item & 7) * 8;
        union { u16 u[8]; uint4 v; } pk;
        #pragma unroll
        for (int j = 0; j < 8; ++j) pk.u[j] = tile[d * 66 + s0 + j];
        *(uint4*)(vt + ((size_t)bh * 64 + d) * S_LEN + stile * 64 + s0) = pk.v;
    }
}

// ---- GEMM16Q: C[M,N] = A[M,K] @ Bt[N,K]^T + bias, quadrant phases ----------
// (R12 — best measured GEMM structure this session.)
template<int NF, bool OUT_BF16>
__global__ __launch_bounds__(512, 2) void gemm16q(
    const u16* __restrict__ A, const u16* __restrict__ Bt,
    const float* __restrict__ bias, void* __restrict__ C,
    int M, int N, int K)
{
    constexpr int NBH = NF / 2;            // B half-tiles (128 rows) per K-tile
    constexpr int BSLOT = NF * 4096;       // u16 per B parity buffer (BN x 64)
    __shared__ __attribute__((aligned(16))) u16 sm[32768 + 2 * BSLOT];
    u16* const As = sm;                    // 4 x 8192 u16: slot (par*2+half)
    u16* const Bs = sm + 32768;            // 2 x BSLOT u16: slot par

    const int tid = threadIdx.x;
    const int wave = tid >> 6, lane = tid & 63;
    const int l15 = lane & 15, q4 = lane >> 4;
    const int wm = wave >> 2, wn = wave & 3;

    // XCD-resident A-panel mapping
    const int bid = (int)blockIdx.x;
    const int xcd = bid & 7;
    const int lx  = bid >> 3;
    const int MB  = M >> 8;                // 32
    const int PM  = MB >> 3;               // 4 rows per XCD panel
    const int nb  = lx / PM;
    const int mb  = xcd * PM + (lx - nb * PM);
    const int m0 = mb << 8, n0 = nb * NF * 64;

    const u16* Ag = A + (size_t)m0 * K;
    const u16* Bg = Bt + (size_t)n0 * K;

    const int srow = tid >> 3;
    const size_t goff0 = (size_t)srow * K + (size_t)(((tid & 7) ^ (srow & 7)) * 8);
    const size_t goff1 = goff0 + (size_t)64 * K;
    const int ldso = tid * 8;

    const int ck0 = (q4 ^ (l15 & 7)) * 8;
    const int ck1 = ((4 + q4) ^ (l15 & 7)) * 8;
    const int rb0 = (wn * NF * 16 + l15) * 64;   // B row base (nf=0)

    f32x4 acc[8][NF] = {};
    const int T = K >> 6;

#define STAGE_A(t_, h_) do { \
    const u16* ga_ = Ag + (size_t)(h_) * 128 * K + (size_t)(t_) * 64; \
    u16* da_ = As + (((t_) & 1) * 2 + (h_)) * 8192; \
    async_load16(ga_ + goff0, da_ + ldso); \
    async_load16(ga_ + goff1, da_ + ldso + 4096); \
} while (0)

#define STAGE_B(t_, h_) do { \
    const u16* gb_ = Bg + (size_t)(h_) * 128 * K + (size_t)(t_) * 64; \
    u16* db_ = Bs + ((t_) & 1) * BSLOT + (h_) * 8192; \
    async_load16(gb_ + goff0, db_ + ldso); \
    async_load16(gb_ + goff1, db_ + ldso + 4096); \
} while (0)

#define LOAD_AF(P_) do { \
    af[0][0] = *(const bf16x8*)(Ah + ((2 * (P_)) * 16 + l15) * 64 + ck0); \
    af[0][1] = *(const bf16x8*)(Ah + ((2 * (P_)) * 16 + l15) * 64 + ck1); \
    af[1][0] = *(const bf16x8*)(Ah + ((2 * (P_) + 1) * 16 + l15) * 64 + ck0); \
    af[1][1] = *(const bf16x8*)(Ah + ((2 * (P_) + 1) * 16 + l15) * 64 + ck1); \
} while (0)

#define PHASE_MFMA(P_) do { \
    __builtin_amdgcn_s_barrier(); \
    __builtin_amdgcn_s_setprio(1); \
    _Pragma("unroll") \
    for (int i_ = 0; i_ < 2; ++i_) \
        _Pragma("unroll") \
        for (int nf_ = 0; nf_ < NF; ++nf_) \
            _Pragma("unroll") \
            for (int kk_ = 0; kk_ < 2; ++kk_) \
                acc[2 * (P_) + i_][nf_] = __builtin_amdgcn_mfma_f32_16x16x32_bf16( \
                    af[i_][kk_], bfr[nf_][kk_], acc[2 * (P_) + i_][nf_], 0, 0, 0); \
    __builtin_amdgcn_s_setprio(0); \
} while (0)

    // prologue: A(0) both halves + B(0) + B(1); keep B(1) in flight
    STAGE_A(0, 0); STAGE_A(0, 1);
    STAGE_B(0, 0); if constexpr (NBH == 2) STAGE_B(0, 1);
    if (T > 1) {
        STAGE_B(1, 0); if constexpr (NBH == 2) STAGE_B(1, 1);
        if constexpr (NBH == 2) asm volatile("s_waitcnt vmcnt(4)");
        else                    asm volatile("s_waitcnt vmcnt(2)");
    } else {
        asm volatile("s_waitcnt vmcnt(0)");
    }
    __builtin_amdgcn_sched_barrier(0);
    __builtin_amdgcn_s_barrier();

    for (int t = 0; t < T; ++t) {
        const int par = t & 1;
        const u16* Ah = As + (par * 2 + wm) * 8192;   // this wave's A half
        const u16* Bl = Bs + par * BSLOT;

        bf16x8 af[2][2], bfr[NF][2];

        // ---- phase 0: ALL bfr (held all tile) + af m-frags 0,1 -------------
        #pragma unroll
        for (int nf = 0; nf < NF; ++nf) {
            bfr[nf][0] = *(const bf16x8*)(Bl + rb0 + nf * (16 * 64) + ck0);
            bfr[nf][1] = *(const bf16x8*)(Bl + rb0 + nf * (16 * 64) + ck1);
        }
        LOAD_AF(0);
        if (t + 1 < T) STAGE_A(t + 1, 0);
        PHASE_MFMA(0);
        __builtin_amdgcn_s_barrier();

        // ---- phase 1: af m-frags 2,3; stage A(t+1).h1 ----------------------
        LOAD_AF(1);
        if (t + 1 < T) STAGE_A(t + 1, 1);
        PHASE_MFMA(1);
        __builtin_amdgcn_s_barrier();

        // ---- phase 2: af m-frags 4,5; stage B(t+2).h0 into B[par] ----------
        LOAD_AF(2);
        if (t + 2 < T) STAGE_B(t + 2, 0);
        PHASE_MFMA(2);
        __builtin_amdgcn_s_barrier();

        // ---- phase 3: af m-frags 6,7; stage B(t+2).h1 ----------------------
        LOAD_AF(3);
        if constexpr (NBH == 2) { if (t + 2 < T) STAGE_B(t + 2, 1); }
        PHASE_MFMA(3);
        if (t + 1 < T) {
            if (t + 2 < T) {
                if constexpr (NBH == 2) asm volatile("s_waitcnt vmcnt(4)");
                else                    asm volatile("s_waitcnt vmcnt(2)");
            } else {
                asm volatile("s_waitcnt vmcnt(0)");
            }
            __builtin_amdgcn_sched_barrier(0);
            __builtin_amdgcn_s_barrier();
        }
    }

#undef STAGE_A
#undef STAGE_B
#undef LOAD_AF
#undef PHASE_MFMA

    // epilogue: C/D col=l15, row=q4*4+r
    #pragma unroll
    for (int mf = 0; mf < 8; ++mf) {
        const int row = m0 + wm * 128 + mf * 16 + q4 * 4;
        #pragma unroll
        for (int nf = 0; nf < NF; ++nf) {
            const int col = n0 + wn * NF * 16 + nf * 16 + l15;
            const float bv = bias[col];
            #pragma unroll
            for (int r = 0; r < 4; ++r) {
                float v = acc[mf][nf][r] + bv;
                if (OUT_BF16) ((u16*)C)[(size_t)(row + r) * N + col] = f2bf(v);
                else          ((float*)C)[(size_t)(row + r) * N + col] = v;
            }
        }
    }
}

// ---- flash attention R6 ----------------------------------------------------
// One Q-tile pass (128 q-rows at qt). Triple-buffered K/V, prefetch-2,
// S^T = K·Q^T -> exp2 -> P^T B-frags in registers -> O^T = V^T·P^T.
__device__ __forceinline__ void stage_tiles(
    const u16* __restrict__ qkv, const u16* __restrict__ vt,
    size_t base, int bh, int h, int w, int srow8, int schunk,
    int kt, u16* __restrict__ KsB, u16* __restrict__ VsB)
{
    #pragma unroll
    for (int q = 0; q < 2; ++q) {
        int rloc = w * 16 + q * 8 + srow8;
        int sc = ((schunk ^ (rloc & 7)) * 8);
        async_load16(qkv + (base + (size_t)kt * 64 + rloc) * (size_t)NQKV + DMODEL + h * HDIM + sc,
                     KsB + (w * 16 + q * 8) * 64);
        async_load16(vt + ((size_t)bh * 64 + rloc) * S_LEN + kt * 64 + sc,
                     VsB + (w * 16 + q * 8) * 64);
    }
}

__device__ __forceinline__ void attn_pass(
    int qt, const u16* __restrict__ qkv, const u16* __restrict__ vt,
    __bf16* __restrict__ outb, u16 (*Ks)[64 * 64], u16 (*Vs)[64 * 64],
    int w, int lane, int bh, int h, size_t base)
{
    const int l15 = lane & 15, q4 = lane >> 4;
    const int srow8 = lane >> 3, schunk = lane & 7;

    // Q fragments for both halves ([n=q=l15][k=d=q4*8+j]); scale folds
    // 1/sqrt(64) * log2(e) so P = 2^(K·Q^T) == e^(K·Q^T/8).
    const float QSCALE = 0.125f * 1.44269504f;
    bf16x8 qf[2][2];
    #pragma unroll
    for (int mh = 0; mh < 2; ++mh) {
        int qrow = qt * 128 + mh * 64 + w * 16 + l15;
        #pragma unroll
        for (int kc = 0; kc < 2; ++kc) {
            bf16x8 raw = *(const bf16x8*)(qkv + (base + qrow) * (size_t)NQKV + h * HDIM + kc * 32 + q4 * 8);
            bf16x8 sc;
            #pragma unroll
            for (int j = 0; j < 8; ++j) sc[j] = (__bf16)((float)raw[j] * QSCALE);
            qf[mh][kc] = sc;
        }
    }

    bf16x4 ones4;
    #pragma unroll
    for (int j = 0; j < 4; ++j) ones4[j] = (__bf16)1.0f;

    f32x4 o0[4] = {}, o1[4] = {};   // O^T: [d-tile mt][q=l15], rows d=q4*4+r
    f32x4 la0 = {}, la1 = {};       // l[q=l15]

    const int ktlast = 2 * qt + 1;  // tail tile (half-0 fully masked)

    __syncthreads();                // protect LDS reuse across passes
    stage_tiles(qkv, vt, base, bh, h, w, srow8, schunk, 0, Ks[0], Vs[0]);
    if (ktlast >= 1)
        stage_tiles(qkv, vt, base, bh, h, w, srow8, schunk, 1, Ks[1], Vs[1]);

    for (int kt = 0; kt <= 2 * qt; ++kt) {
        const int buf = kt % 3;
        __syncthreads();            // kt,kt+1 staged; reads of buf (kt+2)%3 done
        int pf = kt + 2;
        if (pf <= ktlast)
            stage_tiles(qkv, vt, base, bh, h, w, srow8, schunk, pf, Ks[pf % 3], Vs[pf % 3]);

        // S^T = K·Q^T; kf shared across halves
        f32x4 st0[4] = {}, st1[4] = {};
        #pragma unroll
        for (int nt = 0; nt < 4; ++nt) {
            int n = nt * 16 + l15;      // key row in Ks
            #pragma unroll
            for (int kc = 0; kc < 2; ++kc) {
                int ch = (((kc * 4 + q4) ^ (n & 7)) * 8);
                bf16x8 kf = *(const bf16x8*)(&Ks[buf][n * 64 + ch]);
                st0[nt] = __builtin_amdgcn_mfma_f32_16x16x32_bf16(kf, qf[0][kc], st0[nt], 0, 0, 0);
                st1[nt] = __builtin_amdgcn_mfma_f32_16x16x32_bf16(kf, qf[1][kc], st1[nt], 0, 0, 0);
            }
        }

        if (kt == 2 * qt) {             // diagonal for half 0 (uniform branch)
            #pragma unroll
            for (int nt = 0; nt < 4; ++nt)
                #pragma unroll
                for (int r = 0; r < 4; ++r) {
                    int keyl = nt * 16 + q4 * 4 + r;
                    if (keyl > w * 16 + l15) st0[nt][r] = -1e30f;
                }
        }

        // P^T = 2^(S^T) packed to bf16x4 B-frags (k = q4*4+j), in registers
        bf16x4 pb0[4], pb1[4];
        #pragma unroll
        for (int nt = 0; nt < 4; ++nt)
            #pragma unroll
            for (int r = 0; r < 4; ++r) {
                pb0[nt][r] = (__bf16)__builtin_amdgcn_exp2f(st0[nt][r]);
                pb1[nt][r] = (__bf16)__builtin_amdgcn_exp2f(st1[nt][r]);
            }

        // O^T += V^T · P^T  (vf shared across halves); l += ones · P^T
        #pragma unroll
        for (int nt = 0; nt < 4; ++nt) {
            #pragma unroll
            for (int mt = 0; mt < 4; ++mt) {
                int row = mt * 16 + l15;                       // d row in Vs
                int ch = (nt * 2 + (q4 >> 1)) ^ (row & 7);
                bf16x4 vf = *(const bf16x4*)(&Vs[buf][row * 64 + ch * 8 + (q4 & 1) * 4]);
                o0[mt] = mfma16(vf, pb0[nt], o0[mt]);
                o1[mt] = mfma16(vf, pb1[nt], o1[mt]);
            }
            la0 = mfma16(ones4, pb0[nt], la0);
            la1 = mfma16(ones4, pb1[nt], la1);
        }
    }

    // ---- tail tile ktlast: half 0 fully masked; half 1 only ----------------
    {
        const int buf = ktlast % 3;
        __syncthreads();

        f32x4 st1[4] = {};
        #pragma unroll
        for (int nt = 0; nt < 4; ++nt) {
            int n = nt * 16 + l15;
            #pragma unroll
            for (int kc = 0; kc < 2; ++kc) {
                int ch = (((kc * 4 + q4) ^ (n & 7)) * 8);
                bf16x8 kf = *(const bf16x8*)(&Ks[buf][n * 64 + ch]);
                st1[nt] = __builtin_amdgcn_mfma_f32_16x16x32_bf16(kf, qf[1][kc], st1[nt], 0, 0, 0);
            }
        }
        bf16x4 pb1[4];
        #pragma unroll
        for (int nt = 0; nt < 4; ++nt)
            #pragma unroll
            for (int r = 0; r < 4; ++r) {
                int keyl = nt * 16 + q4 * 4 + r;
                float s = (keyl > w * 16 + l15) ? -1e30f : st1[nt][r];
                pb1[nt][r] = (__bf16)__builtin_amdgcn_exp2f(s);
            }
        #pragma unroll
        for (int nt = 0; nt < 4; ++nt) {
            #pragma unroll
            for (int mt = 0; mt < 4; ++mt) {
                int row = mt * 16 + l15;
                int ch = (nt * 2 + (q4 >> 1)) ^ (row & 7);
                bf16x4 vf = *(const bf16x4*)(&Vs[buf][row * 64 + ch * 8 + (q4 & 1) * 4]);
                o1[mt] = mfma16(vf, pb1[nt], o1[mt]);
            }
            la1 = mfma16(ones4, pb1[nt], la1);
        }
    }

    // epilogue: lane holds O^T[d = mt*16+q4*4+r][q=l15]; packed 8B stores
    float inv0 = 1.0f / la0[0], inv1 = 1.0f / la1[0];
    int row0 = qt * 128 + w * 16 + l15;
    int row1 = row0 + 64;
    #pragma unroll
    for (int mt = 0; mt < 4; ++mt) {
        union { __bf16 b[4]; ushort4 v; } p0, p1;
        #pragma unroll
        for (int r = 0; r < 4; ++r) {
            p0.b[r] = (__bf16)(o0[mt][r] * inv0);
            p1.b[r] = (__bf16)(o1[mt][r] * inv1);
        }
        int col = h * HDIM + mt * 16 + q4 * 4;
        *(ushort4*)(&outb[(base + row0) * (size_t)DMODEL + col]) = p0.v;
        *(ushort4*)(&outb[(base + row1) * (size_t)DMODEL + col]) = p1.v;
    }
}

// block = (bx, bh): processes Q-tiles qt = NT-1-bx and qt = bx (34 K-iters
// total for every block -> perfect load balance). gridDim.x = NT/2 = 8.
__global__ __launch_bounds__(256, 3) void attn_kernel(
    const u16* __restrict__ qkv, const u16* __restrict__ vt, u16* __restrict__ out)
{
    __shared__ __attribute__((aligned(16))) u16 Ks[3][64 * 64];
    __shared__ __attribute__((aligned(16))) u16 Vs[3][64 * 64];

    const int tid = threadIdx.x;
    const int w = tid >> 6, lane = tid & 63;
    const int bh = blockIdx.y;
    const int b = bh >> 4, h = bh & 15;
    const size_t base = (size_t)b * S_LEN;
    const int NT = (int)gridDim.x * 2;           // 16

    attn_pass(NT - 1 - (int)blockIdx.x, qkv, vt, (__bf16*)out, Ks, Vs, w, lane, bh, h, base);
    attn_pass((int)blockIdx.x,          qkv, vt, (__bf16*)out, Ks, Vs, w, lane, bh, h, base);
}

extern "C" void kernel_launch(void* const* d_in, const int* in_sizes, int n_in,
                              void* d_out, int out_size, void* d_ws, size_t ws_size,
                              hipStream_t stream) {
    const float* x      = (const float*)d_in[0];
    // d_in[1] = mask (causal tril) — implemented structurally, not read
    const float* w_attn = (const float*)d_in[2];
    const float* b_attn = (const float*)d_in[3];
    const float* w_proj = (const float*)d_in[4];
    const float* b_proj = (const float*)d_in[5];

    u16* xb   = (u16*)d_ws;                                   // 8192x1024 (dead after QKV GEMM)
    u16* wat  = xb  + (size_t)MTOT * DMODEL;                  // 3072x1024
    u16* wpt  = wat + (size_t)NQKV * DMODEL;                  // 1024x1024
    u16* qkv  = wpt + (size_t)DMODEL * DMODEL;                // 8192x3072
    u16* attn = qkv + (size_t)MTOT * NQKV;                    // 8192x1024
    u16* vt   = xb;                                           // Vt[64 bh][64 d][2048 s] aliases xb

    prep_kernel<<<NCONV + NWAT + NWPT, 256, 0, stream>>>(
        (const float4*)x, (ushort4*)xb, w_attn, wat, w_proj, wpt);

    gemm16q<4, true><<<dim3((MTOT / 256) * (NQKV / 256)), 512, 0, stream>>>(
        xb, wat, b_attn, (void*)qkv, MTOT, NQKV, DMODEL);

    transpose_v_kernel<<<dim3(S_LEN / 64, 4 * NHEAD), 256, 0, stream>>>(qkv, vt);

    attn_kernel<<<dim3(S_LEN / 256, 4 * NHEAD), 256, 0, stream>>>(qkv, vt, attn);

    gemm16q<2, false><<<dim3((MTOT / 256) * (DMODEL / 128)), 512, 0, stream>>>(
        attn, wpt, b_proj, d_out, MTOT, DMODEL, DMODEL);
}

// Round 9
// 261.933 us; speedup vs baseline: 1.2802x; 1.0265x over previous
//
#include <hip/hip_runtime.h>
#include <hip/hip_bf16.h>
#include <stdint.h>

// ---------------------------------------------------------------------------
// CausalSelfAttention: x(4,2048,1024) fp32 -> out fp32
// qkv = x@w_attn+b_attn; flash-attn causal (H=16,hd=64); out = attn@w_proj+b_proj
// R15: (1) gemm16q 4 phases -> 2 phases per K-tile (m-frags 0-3 then 4-7).
//   Accounting: per-tile wall ~5430 cyc vs MFMA 2483 + LDS 2313 — the lockstep
//   phase structure serializes reads/MFMA/barriers; halving barrier count
//   (9 -> 5 per tile) attacks the fixed-cost term for BOTH GEMMs (proj, at
//   NF=2, is fixed-cost dominated and gains proportionally more).
//   Staging separation proof unchanged: A(t+1) staged phase 0 (its slots'
//   readers finished last tile, >=1 barrier back); B(t+2) staged phase 1
//   (bfr readers completed before phase-0 MFMA + 2 barriers back).
//   (2) V-transpose fused into QKV epilogue: GEMM writes Q,K to dense qk
//   (stride 2048) and the V third directly TRANSPOSED into vt (8B packed
//   stores, 4 q4-lanes merge into 32B segments). transpose_v kernel deleted
//   (-16MB read -launch). attn reads Q/K at stride 2048.
// attn (R6, best measured ~66.6us): paired Q-tiles, triple-buffered K/V ring.
// Workspace: xb 16MB | wat 6MB | wpt 2MB | qk 32MB | vt 16MB | attn 16MB = 88MB
// ---------------------------------------------------------------------------

typedef uint16_t u16;
typedef __bf16 bf16x8 __attribute__((ext_vector_type(8)));
typedef __bf16 bf16x4 __attribute__((ext_vector_type(4)));
typedef short s16x4 __attribute__((ext_vector_type(4)));
typedef float f32x4 __attribute__((ext_vector_type(4)));

#define S_LEN 2048
#define DMODEL 1024
#define NHEAD 16
#define HDIM 64
#define MTOT 8192   // B*S
#define NQKV 3072
#define QKN 2048    // dense Q|K row stride after fused split

__device__ __forceinline__ u16 f2bf(float f) {
    union { float f; uint32_t u; } v; v.f = f;
    uint32_t u = v.u;
    return (u16)((u + 0x7fffu + ((u >> 16) & 1u)) >> 16);  // RNE
}

__device__ __forceinline__ s16x4 bits4(bf16x4 v) {
    union { bf16x4 b; s16x4 s; } u; u.b = v; return u.s;
}

// D = A*B + C, 16x16x16 bf16 (A,B: 4 bf16/lane, k = q4*4+j)
__device__ __forceinline__ f32x4 mfma16(bf16x4 a, bf16x4 b, f32x4 c) {
    return __builtin_amdgcn_mfma_f32_16x16x16bf16_1k(bits4(a), bits4(b), c, 0, 0, 0);
}

__device__ __forceinline__ void async_load16(const void* g, void* l) {
    __builtin_amdgcn_global_load_lds(
        (__attribute__((address_space(1))) void*)g,
        (__attribute__((address_space(3))) void*)l,
        16, 0, 0);
}

// ---- merged prep: convert x -> bf16 | transpose w_attn | transpose w_proj --
#define NCONV (MTOT * DMODEL / 4 / 256)            // 8192 blocks
#define NWAT  ((NQKV / 64) * (DMODEL / 64))        // 768
#define NWPT  ((DMODEL / 64) * (DMODEL / 64))      // 256

__device__ __forceinline__ void transpose_tile(
    const float* __restrict__ in, u16* __restrict__ out, int R, int C,
    int bx, int by, int tid)
{
    __shared__ float tile[64][65];
    int r0 = by * 64, c0 = bx * 64;
    #pragma unroll
    for (int i = 0; i < 16; ++i) {
        int idx = tid + i * 256;
        int r = idx >> 6, c = idx & 63;
        tile[r][c] = in[(size_t)(r0 + r) * C + c0 + c];
    }
    __syncthreads();
    #pragma unroll
    for (int i = 0; i < 16; ++i) {
        int idx = tid + i * 256;
        int c = idx >> 6, r = idx & 63;
        out[(size_t)(c0 + c) * R + r0 + r] = f2bf(tile[r][c]);
    }
}

__global__ void prep_kernel(
    const float4* __restrict__ x4, ushort4* __restrict__ xb4,
    const float* __restrict__ w_attn, u16* __restrict__ wat,
    const float* __restrict__ w_proj, u16* __restrict__ wpt)
{
    const int bid = blockIdx.x;
    const int tid = threadIdx.x;
    if (bid < NCONV) {
        int i = bid * 256 + tid;
        float4 f = x4[i];
        ushort4 o;
        o.x = f2bf(f.x); o.y = f2bf(f.y); o.z = f2bf(f.z); o.w = f2bf(f.w);
        xb4[i] = o;
    } else if (bid < NCONV + NWAT) {
        int b2 = bid - NCONV;
        transpose_tile(w_attn, wat, DMODEL, NQKV, b2 % (NQKV / 64), b2 / (NQKV / 64), tid);
    } else {
        int b3 = bid - NCONV - NWAT;
        transpose_tile(w_proj, wpt, DMODEL, DMODEL, b3 % (DMODEL / 64), b3 / (DMODEL / 64), tid);
    }
}

// ---- GEMM16Q2: C = A @ Bt^T + bias, 2 phases/K-tile ------------------------
// BM=256, BN=NF*64, BK=64; 8 waves (wm=wave>>2 M, wn=wave&3 N); per-wave
// 128 x NF*16. LDS: A 4 half-slots [par][half] 128x64; B 2 slots [par].
// Chunk-XOR swizzle both-sides (0 conflicts, verified). Per K-tile 2 phases:
//   phase 0: bfr (NF*2) + af m0..3 reads; stage A(t+1) h0+h1; BAR; MFMA m0..3; BAR
//   phase 1: af m4..7 reads; stage B(t+2); BAR; MFMA m4..7;
//   boundary: vmcnt(2*NBH) (B(t+2) in flight, never 0 in-loop); BAR
// OUTMODE 0: fp32 C, stride N (proj). OUTMODE 1: QKV split — cols <2048 ->
// bf16 qk (stride 2048); cols >=2048 -> vt[bh][d][s] transposed 8B stores.
// Mapping: xcd=bid&7 owns fixed 4-mb-row A panel (2MB L2-resident), sweeps nb.
template<int NF, int OUTMODE>
__global__ __launch_bounds__(512, 2) void gemm16q2(
    const u16* __restrict__ A, const u16* __restrict__ Bt,
    const float* __restrict__ bias, void* __restrict__ C,
    u16* __restrict__ vt, int M, int N, int K)
{
    constexpr int NBH = NF / 2;            // B half-tiles per K-tile (2 or 1)
    constexpr int BSLOT = NF * 4096;
    __shared__ __attribute__((aligned(16))) u16 sm[32768 + 2 * BSLOT];
    u16* const As = sm;                    // 4 x 8192: slot (par*2+half)
    u16* const Bs = sm + 32768;            // 2 x BSLOT: slot par

    const int tid = threadIdx.x;
    const int wave = tid >> 6, lane = tid & 63;
    const int l15 = lane & 15, q4 = lane >> 4;
    const int wm = wave >> 2, wn = wave & 3;

    const int bid = (int)blockIdx.x;
    const int xcd = bid & 7;
    const int lx  = bid >> 3;
    const int MB  = M >> 8;                // 32
    const int PM  = MB >> 3;               // 4
    const int nb  = lx / PM;
    const int mb  = xcd * PM + (lx - nb * PM);
    const int m0 = mb << 8, n0 = nb * NF * 64;

    const u16* Ag = A + (size_t)m0 * K;
    const u16* Bg = Bt + (size_t)n0 * K;

    const int srow = tid >> 3;
    const size_t goff0 = (size_t)srow * K + (size_t)(((tid & 7) ^ (srow & 7)) * 8);
    const size_t goff1 = goff0 + (size_t)64 * K;
    const int ldso = tid * 8;

    const int ck0 = (q4 ^ (l15 & 7)) * 8;
    const int ck1 = ((4 + q4) ^ (l15 & 7)) * 8;
    const int rb0 = (wn * NF * 16 + l15) * 64;

    f32x4 acc[8][NF] = {};
    const int T = K >> 6;

#define STAGE_A(t_, h_) do { \
    const u16* ga_ = Ag + (size_t)(h_) * 128 * K + (size_t)(t_) * 64; \
    u16* da_ = As + (((t_) & 1) * 2 + (h_)) * 8192; \
    async_load16(ga_ + goff0, da_ + ldso); \
    async_load16(ga_ + goff1, da_ + ldso + 4096); \
} while (0)

#define STAGE_B(t_, h_) do { \
    const u16* gb_ = Bg + (size_t)(h_) * 128 * K + (size_t)(t_) * 64; \
    u16* db_ = Bs + ((t_) & 1) * BSLOT + (h_) * 8192; \
    async_load16(gb_ + goff0, db_ + ldso); \
    async_load16(gb_ + goff1, db_ + ldso + 4096); \
} while (0)

// af reads for m-frags 4P..4P+3
#define LOAD_AF4(P_) do { \
    _Pragma("unroll") \
    for (int i_ = 0; i_ < 4; ++i_) { \
        af[i_][0] = *(const bf16x8*)(Ah + ((4 * (P_) + i_) * 16 + l15) * 64 + ck0); \
        af[i_][1] = *(const bf16x8*)(Ah + ((4 * (P_) + i_) * 16 + l15) * 64 + ck1); \
    } \
} while (0)

#define PHASE_MFMA4(P_) do { \
    __builtin_amdgcn_s_barrier(); \
    __builtin_amdgcn_s_setprio(1); \
    _Pragma("unroll") \
    for (int i_ = 0; i_ < 4; ++i_) \
        _Pragma("unroll") \
        for (int nf_ = 0; nf_ < NF; ++nf_) \
            _Pragma("unroll") \
            for (int kk_ = 0; kk_ < 2; ++kk_) \
                acc[4 * (P_) + i_][nf_] = __builtin_amdgcn_mfma_f32_16x16x32_bf16( \
                    af[i_][kk_], bfr[nf_][kk_], acc[4 * (P_) + i_][nf_], 0, 0, 0); \
    __builtin_amdgcn_s_setprio(0); \
} while (0)

    // prologue: A(0) both halves + B(0) + B(1); keep B(1) in flight
    STAGE_A(0, 0); STAGE_A(0, 1);
    STAGE_B(0, 0); if constexpr (NBH == 2) STAGE_B(0, 1);
    if (T > 1) {
        STAGE_B(1, 0); if constexpr (NBH == 2) STAGE_B(1, 1);
        if constexpr (NBH == 2) asm volatile("s_waitcnt vmcnt(4)");
        else                    asm volatile("s_waitcnt vmcnt(2)");
    } else {
        asm volatile("s_waitcnt vmcnt(0)");
    }
    __builtin_amdgcn_sched_barrier(0);
    __builtin_amdgcn_s_barrier();

    for (int t = 0; t < T; ++t) {
        const int par = t & 1;
        const u16* Ah = As + (par * 2 + wm) * 8192;
        const u16* Bl = Bs + par * BSLOT;

        bf16x8 af[4][2], bfr[NF][2];

        // ---- phase 0: bfr (all, held) + af m0..3; stage A(t+1) both halves -
        #pragma unroll
        for (int nf = 0; nf < NF; ++nf) {
            bfr[nf][0] = *(const bf16x8*)(Bl + rb0 + nf * (16 * 64) + ck0);
            bfr[nf][1] = *(const bf16x8*)(Bl + rb0 + nf * (16 * 64) + ck1);
        }
        LOAD_AF4(0);
        if (t + 1 < T) { STAGE_A(t + 1, 0); STAGE_A(t + 1, 1); }
        PHASE_MFMA4(0);
        __builtin_amdgcn_s_barrier();

        // ---- phase 1: af m4..7; stage B(t+2) into B[par] -------------------
        LOAD_AF4(1);
        if (t + 2 < T) { STAGE_B(t + 2, 0); if constexpr (NBH == 2) STAGE_B(t + 2, 1); }
        PHASE_MFMA4(1);
        // boundary: A(t+1)+B(t+1) complete; B(t+2) stays in flight
        if (t + 1 < T) {
            if (t + 2 < T) {
                if constexpr (NBH == 2) asm volatile("s_waitcnt vmcnt(4)");
                else                    asm volatile("s_waitcnt vmcnt(2)");
            } else {
                asm volatile("s_waitcnt vmcnt(0)");
            }
            __builtin_amdgcn_sched_barrier(0);
            __builtin_amdgcn_s_barrier();
        }
    }

#undef STAGE_A
#undef STAGE_B
#undef LOAD_AF4
#undef PHASE_MFMA4

    // epilogue: C/D col=l15, row=q4*4+r
    #pragma unroll
    for (int mf = 0; mf < 8; ++mf) {
        const int row = m0 + wm * 128 + mf * 16 + q4 * 4;
        #pragma unroll
        for (int nf = 0; nf < NF; ++nf) {
            const int col0 = n0 + wn * NF * 16 + nf * 16;   // wave-uniform
            const int col = col0 + l15;
            const float bv = bias[col];
            if constexpr (OUTMODE == 0) {
                #pragma unroll
                for (int r = 0; r < 4; ++r)
                    ((float*)C)[(size_t)(row + r) * N + col] = acc[mf][nf][r] + bv;
            } else {
                if (col0 < 2 * DMODEL) {
                    // Q|K -> dense qk, stride QKN
                    #pragma unroll
                    for (int r = 0; r < 4; ++r)
                        ((u16*)C)[(size_t)(row + r) * QKN + col] = f2bf(acc[mf][nf][r] + bv);
                } else {
                    // V -> vt[bh][d][s] transposed; 4 s-consecutive -> 8B store
                    const int vc = col - 2 * DMODEL;         // 0..1023
                    const int bh = (row >> 11) * NHEAD + (vc >> 6);
                    const int dd = vc & 63;
                    const int s  = row & (S_LEN - 1);
                    union { __bf16 b[4]; ushort4 v; } pk;
                    #pragma unroll
                    for (int r = 0; r < 4; ++r)
                        pk.b[r] = (__bf16)(acc[mf][nf][r] + bv);
                    *(ushort4*)(&vt[((size_t)bh * 64 + dd) * S_LEN + s]) = pk.v;
                }
            }
        }
    }
}

// ---- flash attention R6 (Q/K read from dense qk, stride QKN) ---------------
__device__ __forceinline__ void stage_tiles(
    const u16* __restrict__ qk, const u16* __restrict__ vt,
    size_t base, int bh, int h, int w, int srow8, int schunk,
    int kt, u16* __restrict__ KsB, u16* __restrict__ VsB)
{
    #pragma unroll
    for (int q = 0; q < 2; ++q) {
        int rloc = w * 16 + q * 8 + srow8;
        int sc = ((schunk ^ (rloc & 7)) * 8);
        async_load16(qk + (base + (size_t)kt * 64 + rloc) * (size_t)QKN + DMODEL + h * HDIM + sc,
                     KsB + (w * 16 + q * 8) * 64);
        async_load16(vt + ((size_t)bh * 64 + rloc) * S_LEN + kt * 64 + sc,
                     VsB + (w * 16 + q * 8) * 64);
    }
}

__device__ __forceinline__ void attn_pass(
    int qt, const u16* __restrict__ qk, const u16* __restrict__ vt,
    __bf16* __restrict__ outb, u16 (*Ks)[64 * 64], u16 (*Vs)[64 * 64],
    int w, int lane, int bh, int h, size_t base)
{
    const int l15 = lane & 15, q4 = lane >> 4;
    const int srow8 = lane >> 3, schunk = lane & 7;

    // Q fragments for both halves ([n=q=l15][k=d=q4*8+j]); scale folds
    // 1/sqrt(64) * log2(e) so P = 2^(K·Q^T) == e^(K·Q^T/8).
    const float QSCALE = 0.125f * 1.44269504f;
    bf16x8 qf[2][2];
    #pragma unroll
    for (int mh = 0; mh < 2; ++mh) {
        int qrow = qt * 128 + mh * 64 + w * 16 + l15;
        #pragma unroll
        for (int kc = 0; kc < 2; ++kc) {
            bf16x8 raw = *(const bf16x8*)(qk + (base + qrow) * (size_t)QKN + h * HDIM + kc * 32 + q4 * 8);
            bf16x8 sc;
            #pragma unroll
            for (int j = 0; j < 8; ++j) sc[j] = (__bf16)((float)raw[j] * QSCALE);
            qf[mh][kc] = sc;
        }
    }

    bf16x4 ones4;
    #pragma unroll
    for (int j = 0; j < 4; ++j) ones4[j] = (__bf16)1.0f;

    f32x4 o0[4] = {}, o1[4] = {};   // O^T: [d-tile mt][q=l15], rows d=q4*4+r
    f32x4 la0 = {}, la1 = {};       // l[q=l15]

    const int ktlast = 2 * qt + 1;  // tail tile (half-0 fully masked)

    __syncthreads();                // protect LDS reuse across passes
    stage_tiles(qk, vt, base, bh, h, w, srow8, schunk, 0, Ks[0], Vs[0]);
    if (ktlast >= 1)
        stage_tiles(qk, vt, base, bh, h, w, srow8, schunk, 1, Ks[1], Vs[1]);

    for (int kt = 0; kt <= 2 * qt; ++kt) {
        const int buf = kt % 3;
        __syncthreads();            // kt,kt+1 staged; reads of buf (kt+2)%3 done
        int pf = kt + 2;
        if (pf <= ktlast)
            stage_tiles(qk, vt, base, bh, h, w, srow8, schunk, pf, Ks[pf % 3], Vs[pf % 3]);

        // S^T = K·Q^T; kf shared across halves
        f32x4 st0[4] = {}, st1[4] = {};
        #pragma unroll
        for (int nt = 0; nt < 4; ++nt) {
            int n = nt * 16 + l15;      // key row in Ks
            #pragma unroll
            for (int kc = 0; kc < 2; ++kc) {
                int ch = (((kc * 4 + q4) ^ (n & 7)) * 8);
                bf16x8 kf = *(const bf16x8*)(&Ks[buf][n * 64 + ch]);
                st0[nt] = __builtin_amdgcn_mfma_f32_16x16x32_bf16(kf, qf[0][kc], st0[nt], 0, 0, 0);
                st1[nt] = __builtin_amdgcn_mfma_f32_16x16x32_bf16(kf, qf[1][kc], st1[nt], 0, 0, 0);
            }
        }

        if (kt == 2 * qt) {             // diagonal for half 0 (uniform branch)
            #pragma unroll
            for (int nt = 0; nt < 4; ++nt)
                #pragma unroll
                for (int r = 0; r < 4; ++r) {
                    int keyl = nt * 16 + q4 * 4 + r;
                    if (keyl > w * 16 + l15) st0[nt][r] = -1e30f;
                }
        }

        // P^T = 2^(S^T) packed to bf16x4 B-frags (k = q4*4+j), in registers
        bf16x4 pb0[4], pb1[4];
        #pragma unroll
        for (int nt = 0; nt < 4; ++nt)
            #pragma unroll
            for (int r = 0; r < 4; ++r) {
                pb0[nt][r] = (__bf16)__builtin_amdgcn_exp2f(st0[nt][r]);
                pb1[nt][r] = (__bf16)__builtin_amdgcn_exp2f(st1[nt][r]);
            }

        // O^T += V^T · P^T  (vf shared across halves); l += ones · P^T
        #pragma unroll
        for (int nt = 0; nt < 4; ++nt) {
            #pragma unroll
            for (int mt = 0; mt < 4; ++mt) {
                int row = mt * 16 + l15;                       // d row in Vs
                int ch = (nt * 2 + (q4 >> 1)) ^ (row & 7);
                bf16x4 vf = *(const bf16x4*)(&Vs[buf][row * 64 + ch * 8 + (q4 & 1) * 4]);
                o0[mt] = mfma16(vf, pb0[nt], o0[mt]);
                o1[mt] = mfma16(vf, pb1[nt], o1[mt]);
            }
            la0 = mfma16(ones4, pb0[nt], la0);
            la1 = mfma16(ones4, pb1[nt], la1);
        }
    }

    // ---- tail tile ktlast: half 0 fully masked; half 1 only ----------------
    {
        const int buf = ktlast % 3;
        __syncthreads();

        f32x4 st1[4] = {};
        #pragma unroll
        for (int nt = 0; nt < 4; ++nt) {
            int n = nt * 16 + l15;
            #pragma unroll
            for (int kc = 0; kc < 2; ++kc) {
                int ch = (((kc * 4 + q4) ^ (n & 7)) * 8);
                bf16x8 kf = *(const bf16x8*)(&Ks[buf][n * 64 + ch]);
                st1[nt] = __builtin_amdgcn_mfma_f32_16x16x32_bf16(kf, qf[1][kc], st1[nt], 0, 0, 0);
            }
        }
        bf16x4 pb1[4];
        #pragma unroll
        for (int nt = 0; nt < 4; ++nt)
            #pragma unroll
            for (int r = 0; r < 4; ++r) {
                int keyl = nt * 16 + q4 * 4 + r;
                float s = (keyl > w * 16 + l15) ? -1e30f : st1[nt][r];
                pb1[nt][r] = (__bf16)__builtin_amdgcn_exp2f(s);
            }
        #pragma unroll
        for (int nt = 0; nt < 4; ++nt) {
            #pragma unroll
            for (int mt = 0; mt < 4; ++mt) {
                int row = mt * 16 + l15;
                int ch = (nt * 2 + (q4 >> 1)) ^ (row & 7);
                bf16x4 vf = *(const bf16x4*)(&Vs[buf][row * 64 + ch * 8 + (q4 & 1) * 4]);
                o1[mt] = mfma16(vf, pb1[nt], o1[mt]);
            }
            la1 = mfma16(ones4, pb1[nt], la1);
        }
    }

    // epilogue: lane holds O^T[d = mt*16+q4*4+r][q=l15]; packed 8B stores
    float inv0 = 1.0f / la0[0], inv1 = 1.0f / la1[0];
    int row0 = qt * 128 + w * 16 + l15;
    int row1 = row0 + 64;
    #pragma unroll
    for (int mt = 0; mt < 4; ++mt) {
        union { __bf16 b[4]; ushort4 v; } p0, p1;
        #pragma unroll
        for (int r = 0; r < 4; ++r) {
            p0.b[r] = (__bf16)(o0[mt][r] * inv0);
            p1.b[r] = (__bf16)(o1[mt][r] * inv1);
        }
        int col = h * HDIM + mt * 16 + q4 * 4;
        *(ushort4*)(&outb[(base + row0) * (size_t)DMODEL + col]) = p0.v;
        *(ushort4*)(&outb[(base + row1) * (size_t)DMODEL + col]) = p1.v;
    }
}

// block = (bx, bh): processes Q-tiles qt = NT-1-bx and qt = bx (34 K-iters
// total for every block -> perfect load balance). gridDim.x = NT/2 = 8.
__global__ __launch_bounds__(256, 3) void attn_kernel(
    const u16* __restrict__ qk, const u16* __restrict__ vt, u16* __restrict__ out)
{
    __shared__ __attribute__((aligned(16))) u16 Ks[3][64 * 64];
    __shared__ __attribute__((aligned(16))) u16 Vs[3][64 * 64];

    const int tid = threadIdx.x;
    const int w = tid >> 6, lane = tid & 63;
    const int bh = blockIdx.y;
    const int b = bh >> 4, h = bh & 15;
    const size_t base = (size_t)b * S_LEN;
    const int NT = (int)gridDim.x * 2;           // 16

    attn_pass(NT - 1 - (int)blockIdx.x, qk, vt, (__bf16*)out, Ks, Vs, w, lane, bh, h, base);
    attn_pass((int)blockIdx.x,          qk, vt, (__bf16*)out, Ks, Vs, w, lane, bh, h, base);
}

extern "C" void kernel_launch(void* const* d_in, const int* in_sizes, int n_in,
                              void* d_out, int out_size, void* d_ws, size_t ws_size,
                              hipStream_t stream) {
    const float* x      = (const float*)d_in[0];
    // d_in[1] = mask (causal tril) — implemented structurally, not read
    const float* w_attn = (const float*)d_in[2];
    const float* b_attn = (const float*)d_in[3];
    const float* w_proj = (const float*)d_in[4];
    const float* b_proj = (const float*)d_in[5];

    u16* xb   = (u16*)d_ws;                                   // 8192x1024
    u16* wat  = xb  + (size_t)MTOT * DMODEL;                  // 3072x1024
    u16* wpt  = wat + (size_t)NQKV * DMODEL;                  // 1024x1024
    u16* qk   = wpt + (size_t)DMODEL * DMODEL;                // 8192x2048 (Q|K dense)
    u16* vt   = qk  + (size_t)MTOT * QKN;                     // Vt[64 bh][64 d][2048 s]
    u16* attn = vt  + (size_t)64 * 64 * S_LEN;                // 8192x1024

    prep_kernel<<<NCONV + NWAT + NWPT, 256, 0, stream>>>(
        (const float4*)x, (ushort4*)xb, w_attn, wat, w_proj, wpt);

    gemm16q2<4, 1><<<dim3((MTOT / 256) * (NQKV / 256)), 512, 0, stream>>>(
        xb, wat, b_attn, (void*)qk, vt, MTOT, NQKV, DMODEL);

    attn_kernel<<<dim3(S_LEN / 256, 4 * NHEAD), 256, 0, stream>>>(qk, vt, attn);

    gemm16q2<2, 0><<<dim3((MTOT / 256) * (DMODEL / 128)), 512, 0, stream>>>(
        attn, wpt, b_proj, d_out, nullptr, MTOT, DMODEL, DMODEL);
}

// Round 10
// 261.299 us; speedup vs baseline: 1.2834x; 1.0024x over previous
//
#include <hip/hip_runtime.h>
#include <hip/hip_bf16.h>
#include <stdint.h>

// ---------------------------------------------------------------------------
// CausalSelfAttention: x(4,2048,1024) fp32 -> out fp32
// qkv = x@w_attn+b_attn; flash-attn causal (H=16,hd=64); out = attn@w_proj+b_proj
// R16: A/B isolation. R15 bundled two changes: V-fusion (-14us, keep) and
//   2-phase K-loop (QKV 72.4 -> 79.4us, revert). This round: exact R12
//   4-phase K-loop (best measured GEMM: 72.4us QKV, 0 conflicts, FETCH 41MB)
//   + R15's fused OUTMODE epilogue (Q,K -> dense qk stride 2048; V -> vt
//   transposed; transpose_v kernel deleted). lgkmcnt(8) pacing hint restored
//   in phase 0 (NF=4). If QKV stays ~79 the V-scatter epilogue is the cost
//   (next: LDS-staged V epilogue); if ~72, 2-phase was the regression.
// attn (R6, ~66.6us measured): paired Q-tiles, triple-buffered K/V ring,
//   Q/K read from dense qk (stride 2048).
// Workspace: xb 16MB | wat 6MB | wpt 2MB | qk 32MB | vt 16MB | attn 16MB = 88MB
// ---------------------------------------------------------------------------

typedef uint16_t u16;
typedef __bf16 bf16x8 __attribute__((ext_vector_type(8)));
typedef __bf16 bf16x4 __attribute__((ext_vector_type(4)));
typedef short s16x4 __attribute__((ext_vector_type(4)));
typedef float f32x4 __attribute__((ext_vector_type(4)));

#define S_LEN 2048
#define DMODEL 1024
#define NHEAD 16
#define HDIM 64
#define MTOT 8192   // B*S
#define NQKV 3072
#define QKN 2048    // dense Q|K row stride after fused split

__device__ __forceinline__ u16 f2bf(float f) {
    union { float f; uint32_t u; } v; v.f = f;
    uint32_t u = v.u;
    return (u16)((u + 0x7fffu + ((u >> 16) & 1u)) >> 16);  // RNE
}

__device__ __forceinline__ s16x4 bits4(bf16x4 v) {
    union { bf16x4 b; s16x4 s; } u; u.b = v; return u.s;
}

// D = A*B + C, 16x16x16 bf16 (A,B: 4 bf16/lane, k = q4*4+j)
__device__ __forceinline__ f32x4 mfma16(bf16x4 a, bf16x4 b, f32x4 c) {
    return __builtin_amdgcn_mfma_f32_16x16x16bf16_1k(bits4(a), bits4(b), c, 0, 0, 0);
}

__device__ __forceinline__ void async_load16(const void* g, void* l) {
    __builtin_amdgcn_global_load_lds(
        (__attribute__((address_space(1))) void*)g,
        (__attribute__((address_space(3))) void*)l,
        16, 0, 0);
}

// ---- merged prep: convert x -> bf16 | transpose w_attn | transpose w_proj --
#define NCONV (MTOT * DMODEL / 4 / 256)            // 8192 blocks
#define NWAT  ((NQKV / 64) * (DMODEL / 64))        // 768
#define NWPT  ((DMODEL / 64) * (DMODEL / 64))      // 256

__device__ __forceinline__ void transpose_tile(
    const float* __restrict__ in, u16* __restrict__ out, int R, int C,
    int bx, int by, int tid)
{
    __shared__ float tile[64][65];
    int r0 = by * 64, c0 = bx * 64;
    #pragma unroll
    for (int i = 0; i < 16; ++i) {
        int idx = tid + i * 256;
        int r = idx >> 6, c = idx & 63;
        tile[r][c] = in[(size_t)(r0 + r) * C + c0 + c];
    }
    __syncthreads();
    #pragma unroll
    for (int i = 0; i < 16; ++i) {
        int idx = tid + i * 256;
        int c = idx >> 6, r = idx & 63;
        out[(size_t)(c0 + c) * R + r0 + r] = f2bf(tile[r][c]);
    }
}

__global__ void prep_kernel(
    const float4* __restrict__ x4, ushort4* __restrict__ xb4,
    const float* __restrict__ w_attn, u16* __restrict__ wat,
    const float* __restrict__ w_proj, u16* __restrict__ wpt)
{
    const int bid = blockIdx.x;
    const int tid = threadIdx.x;
    if (bid < NCONV) {
        int i = bid * 256 + tid;
        float4 f = x4[i];
        ushort4 o;
        o.x = f2bf(f.x); o.y = f2bf(f.y); o.z = f2bf(f.z); o.w = f2bf(f.w);
        xb4[i] = o;
    } else if (bid < NCONV + NWAT) {
        int b2 = bid - NCONV;
        transpose_tile(w_attn, wat, DMODEL, NQKV, b2 % (NQKV / 64), b2 / (NQKV / 64), tid);
    } else {
        int b3 = bid - NCONV - NWAT;
        transpose_tile(w_proj, wpt, DMODEL, DMODEL, b3 % (DMODEL / 64), b3 / (DMODEL / 64), tid);
    }
}

// ---- GEMM16Q: C = A @ Bt^T + bias, 4 quadrant phases (R12 structure) -------
// BM=256, BN=NF*64, BK=64; 8 waves (wm=wave>>2 M, wn=wave&3 N); per-wave
// 128 x NF*16 (mf 0..7, nf 0..NF-1, 16x16x32 MFMA). LDS: A 4 half-slots
// [par][half] 128x64; B 2 slots [par] BNx64. Chunk-XOR swizzle both-sides
// (0 conflicts verified). Phase p: {af reads m-frags 2p,2p+1 (+ all bfr in
// p0) | stage 1 half-tile | BAR | setprio+MFMA(disjoint acc)+setprio | BAR}.
// Staging: p0/p1 A(t+1) halves; p2/p3 B(t+2) into live parity (safe: bfr
// retired by p0 MFMA + 2 barriers). Boundary: counted vmcnt, never 0 in-loop.
// OUTMODE 0: fp32 C stride N (proj). OUTMODE 1: QKV split — cols<2048 ->
// bf16 qk stride 2048; cols>=2048 -> vt[bh][d][s] transposed 8B stores.
// Mapping: xcd=bid&7 owns fixed 4-mb-row A panel (2MB L2-resident), sweeps nb.
template<int NF, int OUTMODE>
__global__ __launch_bounds__(512, 2) void gemm16q(
    const u16* __restrict__ A, const u16* __restrict__ Bt,
    const float* __restrict__ bias, void* __restrict__ C,
    u16* __restrict__ vt, int M, int N, int K)
{
    constexpr int NBH = NF / 2;            // B half-tiles per K-tile (2 or 1)
    constexpr int BSLOT = NF * 4096;       // u16 per B parity buffer
    __shared__ __attribute__((aligned(16))) u16 sm[32768 + 2 * BSLOT];
    u16* const As = sm;                    // 4 x 8192: slot (par*2+half)
    u16* const Bs = sm + 32768;            // 2 x BSLOT: slot par

    const int tid = threadIdx.x;
    const int wave = tid >> 6, lane = tid & 63;
    const int l15 = lane & 15, q4 = lane >> 4;
    const int wm = wave >> 2, wn = wave & 3;

    const int bid = (int)blockIdx.x;
    const int xcd = bid & 7;
    const int lx  = bid >> 3;
    const int MB  = M >> 8;                // 32
    const int PM  = MB >> 3;               // 4
    const int nb  = lx / PM;
    const int mb  = xcd * PM + (lx - nb * PM);
    const int m0 = mb << 8, n0 = nb * NF * 64;

    const u16* Ag = A + (size_t)m0 * K;
    const u16* Bg = Bt + (size_t)n0 * K;

    const int srow = tid >> 3;
    const size_t goff0 = (size_t)srow * K + (size_t)(((tid & 7) ^ (srow & 7)) * 8);
    const size_t goff1 = goff0 + (size_t)64 * K;
    const int ldso = tid * 8;

    const int ck0 = (q4 ^ (l15 & 7)) * 8;
    const int ck1 = ((4 + q4) ^ (l15 & 7)) * 8;
    const int rb0 = (wn * NF * 16 + l15) * 64;   // B row base (nf=0)

    f32x4 acc[8][NF] = {};
    const int T = K >> 6;

#define STAGE_A(t_, h_) do { \
    const u16* ga_ = Ag + (size_t)(h_) * 128 * K + (size_t)(t_) * 64; \
    u16* da_ = As + (((t_) & 1) * 2 + (h_)) * 8192; \
    async_load16(ga_ + goff0, da_ + ldso); \
    async_load16(ga_ + goff1, da_ + ldso + 4096); \
} while (0)

#define STAGE_B(t_, h_) do { \
    const u16* gb_ = Bg + (size_t)(h_) * 128 * K + (size_t)(t_) * 64; \
    u16* db_ = Bs + ((t_) & 1) * BSLOT + (h_) * 8192; \
    async_load16(gb_ + goff0, db_ + ldso); \
    async_load16(gb_ + goff1, db_ + ldso + 4096); \
} while (0)

#define LOAD_AF(P_) do { \
    af[0][0] = *(const bf16x8*)(Ah + ((2 * (P_)) * 16 + l15) * 64 + ck0); \
    af[0][1] = *(const bf16x8*)(Ah + ((2 * (P_)) * 16 + l15) * 64 + ck1); \
    af[1][0] = *(const bf16x8*)(Ah + ((2 * (P_) + 1) * 16 + l15) * 64 + ck0); \
    af[1][1] = *(const bf16x8*)(Ah + ((2 * (P_) + 1) * 16 + l15) * 64 + ck1); \
} while (0)

#define PHASE_MFMA(P_) do { \
    __builtin_amdgcn_s_barrier(); \
    __builtin_amdgcn_s_setprio(1); \
    _Pragma("unroll") \
    for (int i_ = 0; i_ < 2; ++i_) \
        _Pragma("unroll") \
        for (int nf_ = 0; nf_ < NF; ++nf_) \
            _Pragma("unroll") \
            for (int kk_ = 0; kk_ < 2; ++kk_) \
                acc[2 * (P_) + i_][nf_] = __builtin_amdgcn_mfma_f32_16x16x32_bf16( \
                    af[i_][kk_], bfr[nf_][kk_], acc[2 * (P_) + i_][nf_], 0, 0, 0); \
    __builtin_amdgcn_s_setprio(0); \
} while (0)

    // prologue: A(0) both halves + B(0) + B(1); keep B(1) in flight
    STAGE_A(0, 0); STAGE_A(0, 1);
    STAGE_B(0, 0); if constexpr (NBH == 2) STAGE_B(0, 1);
    if (T > 1) {
        STAGE_B(1, 0); if constexpr (NBH == 2) STAGE_B(1, 1);
        if constexpr (NBH == 2) asm volatile("s_waitcnt vmcnt(4)");
        else                    asm volatile("s_waitcnt vmcnt(2)");
    } else {
        asm volatile("s_waitcnt vmcnt(0)");
    }
    __builtin_amdgcn_sched_barrier(0);
    __builtin_amdgcn_s_barrier();

    for (int t = 0; t < T; ++t) {
        const int par = t & 1;
        const u16* Ah = As + (par * 2 + wm) * 8192;   // this wave's A half
        const u16* Bl = Bs + par * BSLOT;

        bf16x8 af[2][2], bfr[NF][2];

        // ---- phase 0: ALL bfr (held all tile) + af m-frags 0,1;
        //               stage A(t+1).h0 --------------------------------------
        #pragma unroll
        for (int nf = 0; nf < NF; ++nf) {
            bfr[nf][0] = *(const bf16x8*)(Bl + rb0 + nf * (16 * 64) + ck0);
            bfr[nf][1] = *(const bf16x8*)(Bl + rb0 + nf * (16 * 64) + ck1);
        }
        LOAD_AF(0);
        if (t + 1 < T) STAGE_A(t + 1, 0);
        if constexpr (NF == 4)    // pace the 12-read burst (m201 hint)
            asm volatile("s_waitcnt lgkmcnt(8)");
        PHASE_MFMA(0);
        __builtin_amdgcn_s_barrier();

        // ---- phase 1: af m-frags 2,3; stage A(t+1).h1 ----------------------
        LOAD_AF(1);
        if (t + 1 < T) STAGE_A(t + 1, 1);
        PHASE_MFMA(1);
        __builtin_amdgcn_s_barrier();

        // ---- phase 2: af m-frags 4,5; stage B(t+2).h0 into B[par] ----------
        LOAD_AF(2);
        if (t + 2 < T) STAGE_B(t + 2, 0);
        PHASE_MFMA(2);
        __builtin_amdgcn_s_barrier();

        // ---- phase 3: af m-frags 6,7; stage B(t+2).h1 ----------------------
        LOAD_AF(3);
        if constexpr (NBH == 2) { if (t + 2 < T) STAGE_B(t + 2, 1); }
        PHASE_MFMA(3);
        // boundary: A(t+1)+B(t+1) complete; B(t+2) loads stay in flight
        if (t + 1 < T) {
            if (t + 2 < T) {
                if constexpr (NBH == 2) asm volatile("s_waitcnt vmcnt(4)");
                else                    asm volatile("s_waitcnt vmcnt(2)");
            } else {
                asm volatile("s_waitcnt vmcnt(0)");
            }
            __builtin_amdgcn_sched_barrier(0);
            __builtin_amdgcn_s_barrier();
        }
    }

#undef STAGE_A
#undef STAGE_B
#undef LOAD_AF
#undef PHASE_MFMA

    // epilogue: C/D col=l15, row=q4*4+r
    #pragma unroll
    for (int mf = 0; mf < 8; ++mf) {
        const int row = m0 + wm * 128 + mf * 16 + q4 * 4;
        #pragma unroll
        for (int nf = 0; nf < NF; ++nf) {
            const int col0 = n0 + wn * NF * 16 + nf * 16;   // wave-uniform
            const int col = col0 + l15;
            const float bv = bias[col];
            if constexpr (OUTMODE == 0) {
                #pragma unroll
                for (int r = 0; r < 4; ++r)
                    ((float*)C)[(size_t)(row + r) * N + col] = acc[mf][nf][r] + bv;
            } else {
                if (col0 < 2 * DMODEL) {
                    // Q|K -> dense qk, stride QKN
                    #pragma unroll
                    for (int r = 0; r < 4; ++r)
                        ((u16*)C)[(size_t)(row + r) * QKN + col] = f2bf(acc[mf][nf][r] + bv);
                } else {
                    // V -> vt[bh][d][s] transposed; 4 s-consecutive -> 8B store
                    const int vc = col - 2 * DMODEL;         // 0..1023
                    const int bh = (row >> 11) * NHEAD + (vc >> 6);
                    const int dd = vc & 63;
                    const int s  = row & (S_LEN - 1);
                    union { __bf16 b[4]; ushort4 v; } pk;
                    #pragma unroll
                    for (int r = 0; r < 4; ++r)
                        pk.b[r] = (__bf16)(acc[mf][nf][r] + bv);
                    *(ushort4*)(&vt[((size_t)bh * 64 + dd) * S_LEN + s]) = pk.v;
                }
            }
        }
    }
}

// ---- flash attention R6 (Q/K read from dense qk, stride QKN) ---------------
__device__ __forceinline__ void stage_tiles(
    const u16* __restrict__ qk, const u16* __restrict__ vt,
    size_t base, int bh, int h, int w, int srow8, int schunk,
    int kt, u16* __restrict__ KsB, u16* __restrict__ VsB)
{
    #pragma unroll
    for (int q = 0; q < 2; ++q) {
        int rloc = w * 16 + q * 8 + srow8;
        int sc = ((schunk ^ (rloc & 7)) * 8);
        async_load16(qk + (base + (size_t)kt * 64 + rloc) * (size_t)QKN + DMODEL + h * HDIM + sc,
                     KsB + (w * 16 + q * 8) * 64);
        async_load16(vt + ((size_t)bh * 64 + rloc) * S_LEN + kt * 64 + sc,
                     VsB + (w * 16 + q * 8) * 64);
    }
}

__device__ __forceinline__ void attn_pass(
    int qt, const u16* __restrict__ qk, const u16* __restrict__ vt,
    __bf16* __restrict__ outb, u16 (*Ks)[64 * 64], u16 (*Vs)[64 * 64],
    int w, int lane, int bh, int h, size_t base)
{
    const int l15 = lane & 15, q4 = lane >> 4;
    const int srow8 = lane >> 3, schunk = lane & 7;

    // Q fragments for both halves ([n=q=l15][k=d=q4*8+j]); scale folds
    // 1/sqrt(64) * log2(e) so P = 2^(K·Q^T) == e^(K·Q^T/8).
    const float QSCALE = 0.125f * 1.44269504f;
    bf16x8 qf[2][2];
    #pragma unroll
    for (int mh = 0; mh < 2; ++mh) {
        int qrow = qt * 128 + mh * 64 + w * 16 + l15;
        #pragma unroll
        for (int kc = 0; kc < 2; ++kc) {
            bf16x8 raw = *(const bf16x8*)(qk + (base + qrow) * (size_t)QKN + h * HDIM + kc * 32 + q4 * 8);
            bf16x8 sc;
            #pragma unroll
            for (int j = 0; j < 8; ++j) sc[j] = (__bf16)((float)raw[j] * QSCALE);
            qf[mh][kc] = sc;
        }
    }

    bf16x4 ones4;
    #pragma unroll
    for (int j = 0; j < 4; ++j) ones4[j] = (__bf16)1.0f;

    f32x4 o0[4] = {}, o1[4] = {};   // O^T: [d-tile mt][q=l15], rows d=q4*4+r
    f32x4 la0 = {}, la1 = {};       // l[q=l15]

    const int ktlast = 2 * qt + 1;  // tail tile (half-0 fully masked)

    __syncthreads();                // protect LDS reuse across passes
    stage_tiles(qk, vt, base, bh, h, w, srow8, schunk, 0, Ks[0], Vs[0]);
    if (ktlast >= 1)
        stage_tiles(qk, vt, base, bh, h, w, srow8, schunk, 1, Ks[1], Vs[1]);

    for (int kt = 0; kt <= 2 * qt; ++kt) {
        const int buf = kt % 3;
        __syncthreads();            // kt,kt+1 staged; reads of buf (kt+2)%3 done
        int pf = kt + 2;
        if (pf <= ktlast)
            stage_tiles(qk, vt, base, bh, h, w, srow8, schunk, pf, Ks[pf % 3], Vs[pf % 3]);

        // S^T = K·Q^T; kf shared across halves
        f32x4 st0[4] = {}, st1[4] = {};
        #pragma unroll
        for (int nt = 0; nt < 4; ++nt) {
            int n = nt * 16 + l15;      // key row in Ks
            #pragma unroll
            for (int kc = 0; kc < 2; ++kc) {
                int ch = (((kc * 4 + q4) ^ (n & 7)) * 8);
                bf16x8 kf = *(const bf16x8*)(&Ks[buf][n * 64 + ch]);
                st0[nt] = __builtin_amdgcn_mfma_f32_16x16x32_bf16(kf, qf[0][kc], st0[nt], 0, 0, 0);
                st1[nt] = __builtin_amdgcn_mfma_f32_16x16x32_bf16(kf, qf[1][kc], st1[nt], 0, 0, 0);
            }
        }

        if (kt == 2 * qt) {             // diagonal for half 0 (uniform branch)
            #pragma unroll
            for (int nt = 0; nt < 4; ++nt)
                #pragma unroll
                for (int r = 0; r < 4; ++r) {
                    int keyl = nt * 16 + q4 * 4 + r;
                    if (keyl > w * 16 + l15) st0[nt][r] = -1e30f;
                }
        }

        // P^T = 2^(S^T) packed to bf16x4 B-frags (k = q4*4+j), in registers
        bf16x4 pb0[4], pb1[4];
        #pragma unroll
        for (int nt = 0; nt < 4; ++nt)
            #pragma unroll
            for (int r = 0; r < 4; ++r) {
                pb0[nt][r] = (__bf16)__builtin_amdgcn_exp2f(st0[nt][r]);
                pb1[nt][r] = (__bf16)__builtin_amdgcn_exp2f(st1[nt][r]);
            }

        // O^T += V^T · P^T  (vf shared across halves); l += ones · P^T
        #pragma unroll
        for (int nt = 0; nt < 4; ++nt) {
            #pragma unroll
            for (int mt = 0; mt < 4; ++mt) {
                int row = mt * 16 + l15;                       // d row in Vs
                int ch = (nt * 2 + (q4 >> 1)) ^ (row & 7);
                bf16x4 vf = *(const bf16x4*)(&Vs[buf][row * 64 + ch * 8 + (q4 & 1) * 4]);
                o0[mt] = mfma16(vf, pb0[nt], o0[mt]);
                o1[mt] = mfma16(vf, pb1[nt], o1[mt]);
            }
            la0 = mfma16(ones4, pb0[nt], la0);
            la1 = mfma16(ones4, pb1[nt], la1);
        }
    }

    // ---- tail tile ktlast: half 0 fully masked; half 1 only ----------------
    {
        const int buf = ktlast % 3;
        __syncthreads();

        f32x4 st1[4] = {};
        #pragma unroll
        for (int nt = 0; nt < 4; ++nt) {
            int n = nt * 16 + l15;
            #pragma unroll
            for (int kc = 0; kc < 2; ++kc) {
                int ch = (((kc * 4 + q4) ^ (n & 7)) * 8);
                bf16x8 kf = *(const bf16x8*)(&Ks[buf][n * 64 + ch]);
                st1[nt] = __builtin_amdgcn_mfma_f32_16x16x32_bf16(kf, qf[1][kc], st1[nt], 0, 0, 0);
            }
        }
        bf16x4 pb1[4];
        #pragma unroll
        for (int nt = 0; nt < 4; ++nt)
            #pragma unroll
            for (int r = 0; r < 4; ++r) {
                int keyl = nt * 16 + q4 * 4 + r;
                float s = (keyl > w * 16 + l15) ? -1e30f : st1[nt][r];
                pb1[nt][r] = (__bf16)__builtin_amdgcn_exp2f(s);
            }
        #pragma unroll
        for (int nt = 0; nt < 4; ++nt) {
            #pragma unroll
            for (int mt = 0; mt < 4; ++mt) {
                int row = mt * 16 + l15;
                int ch = (nt * 2 + (q4 >> 1)) ^ (row & 7);
                bf16x4 vf = *(const bf16x4*)(&Vs[buf][row * 64 + ch * 8 + (q4 & 1) * 4]);
                o1[mt] = mfma16(vf, pb1[nt], o1[mt]);
            }
            la1 = mfma16(ones4, pb1[nt], la1);
        }
    }

    // epilogue: lane holds O^T[d = mt*16+q4*4+r][q=l15]; packed 8B stores
    float inv0 = 1.0f / la0[0], inv1 = 1.0f / la1[0];
    int row0 = qt * 128 + w * 16 + l15;
    int row1 = row0 + 64;
    #pragma unroll
    for (int mt = 0; mt < 4; ++mt) {
        union { __bf16 b[4]; ushort4 v; } p0, p1;
        #pragma unroll
        for (int r = 0; r < 4; ++r) {
            p0.b[r] = (__bf16)(o0[mt][r] * inv0);
            p1.b[r] = (__bf16)(o1[mt][r] * inv1);
        }
        int col = h * HDIM + mt * 16 + q4 * 4;
        *(ushort4*)(&outb[(base + row0) * (size_t)DMODEL + col]) = p0.v;
        *(ushort4*)(&outb[(base + row1) * (size_t)DMODEL + col]) = p1.v;
    }
}

// block = (bx, bh): processes Q-tiles qt = NT-1-bx and qt = bx (34 K-iters
// total for every block -> perfect load balance). gridDim.x = NT/2 = 8.
__global__ __launch_bounds__(256, 3) void attn_kernel(
    const u16* __restrict__ qk, const u16* __restrict__ vt, u16* __restrict__ out)
{
    __shared__ __attribute__((aligned(16))) u16 Ks[3][64 * 64];
    __shared__ __attribute__((aligned(16))) u16 Vs[3][64 * 64];

    const int tid = threadIdx.x;
    const int w = tid >> 6, lane = tid & 63;
    const int bh = blockIdx.y;
    const int b = bh >> 4, h = bh & 15;
    const size_t base = (size_t)b * S_LEN;
    const int NT = (int)gridDim.x * 2;           // 16

    attn_pass(NT - 1 - (int)blockIdx.x, qk, vt, (__bf16*)out, Ks, Vs, w, lane, bh, h, base);
    attn_pass((int)blockIdx.x,          qk, vt, (__bf16*)out, Ks, Vs, w, lane, bh, h, base);
}

extern "C" void kernel_launch(void* const* d_in, const int* in_sizes, int n_in,
                              void* d_out, int out_size, void* d_ws, size_t ws_size,
                              hipStream_t stream) {
    const float* x      = (const float*)d_in[0];
    // d_in[1] = mask (causal tril) — implemented structurally, not read
    const float* w_attn = (const float*)d_in[2];
    const float* b_attn = (const float*)d_in[3];
    const float* w_proj = (const float*)d_in[4];
    const float* b_proj = (const float*)d_in[5];

    u16* xb   = (u16*)d_ws;                                   // 8192x1024
    u16* wat  = xb  + (size_t)MTOT * DMODEL;                  // 3072x1024
    u16* wpt  = wat + (size_t)NQKV * DMODEL;                  // 1024x1024
    u16* qk   = wpt + (size_t)DMODEL * DMODEL;                // 8192x2048 (Q|K dense)
    u16* vt   = qk  + (size_t)MTOT * QKN;                     // Vt[64 bh][64 d][2048 s]
    u16* attn = vt  + (size_t)64 * 64 * S_LEN;                // 8192x1024

    prep_kernel<<<NCONV + NWAT + NWPT, 256, 0, stream>>>(
        (const float4*)x, (ushort4*)xb, w_attn, wat, w_proj, wpt);

    gemm16q<4, 1><<<dim3((MTOT / 256) * (NQKV / 256)), 512, 0, stream>>>(
        xb, wat, b_attn, (void*)qk, vt, MTOT, NQKV, DMODEL);

    attn_kernel<<<dim3(S_LEN / 256, 4 * NHEAD), 256, 0, stream>>>(qk, vt, attn);

    gemm16q<2, 0><<<dim3((MTOT / 256) * (DMODEL / 128)), 512, 0, stream>>>(
        attn, wpt, b_proj, d_out, nullptr, MTOT, DMODEL, DMODEL);
}

// Round 11
// 255.790 us; speedup vs baseline: 1.3110x; 1.0215x over previous
//
#include <hip/hip_runtime.h>
#include <hip/hip_bf16.h>
#include <stdint.h>

// ---------------------------------------------------------------------------
// CausalSelfAttention: x(4,2048,1024) fp32 -> out fp32
// qkv = x@w_attn+b_attn; flash-attn causal (H=16,hd=64); out = attn@w_proj+b_proj
// R17: V-epilogue through LDS. R16's A/B showed the fused V-SCATTER epilogue
//   cost ~10us inside QKV (83.2 vs R12's 72.4): 8B stores at 4KB lane-stride
//   = 16 transactions per 16-lane group. Fix: after the K-loop the 128KB LDS
//   is dead and a V-block's output (256 s x 256 d x 2B) fits it EXACTLY.
//   acc -> LDS [d'][s-granule ^ (d'&63)] (XOR keeps write banks spread),
//   barrier, read back, store 128B-contiguous runs into vt (16 lanes x 8B
//   consecutive s). V-blocks are block-uniform (BN=256 divides the QK/V
//   boundary). Also removed the lgkmcnt(8) hint R16 re-added — K-loop is now
//   byte-identical to R12's best-measured structure (72.4us QKV).
// gemm16q (R12 K-loop): quadrant phases, intrinsic barriers, counted vmcnt,
//   chunk-XOR swizzle (0 conflicts), XCD A-panel mapping (FETCH 41MB).
//   QKV NF=4 grid 384; proj NF=2 grid 256.
// attn (R6, ~66.6us measured): paired Q-tiles, triple-buffered K/V ring,
//   Q/K read from dense qk (stride 2048).
// Workspace: xb 16MB | wat 6MB | wpt 2MB | qk 32MB | vt 16MB | attn 16MB = 88MB
// ---------------------------------------------------------------------------

typedef uint16_t u16;
typedef __bf16 bf16x8 __attribute__((ext_vector_type(8)));
typedef __bf16 bf16x4 __attribute__((ext_vector_type(4)));
typedef short s16x4 __attribute__((ext_vector_type(4)));
typedef float f32x4 __attribute__((ext_vector_type(4)));

#define S_LEN 2048
#define DMODEL 1024
#define NHEAD 16
#define HDIM 64
#define MTOT 8192   // B*S
#define NQKV 3072
#define QKN 2048    // dense Q|K row stride after fused split

__device__ __forceinline__ u16 f2bf(float f) {
    union { float f; uint32_t u; } v; v.f = f;
    uint32_t u = v.u;
    return (u16)((u + 0x7fffu + ((u >> 16) & 1u)) >> 16);  // RNE
}

__device__ __forceinline__ s16x4 bits4(bf16x4 v) {
    union { bf16x4 b; s16x4 s; } u; u.b = v; return u.s;
}

// D = A*B + C, 16x16x16 bf16 (A,B: 4 bf16/lane, k = q4*4+j)
__device__ __forceinline__ f32x4 mfma16(bf16x4 a, bf16x4 b, f32x4 c) {
    return __builtin_amdgcn_mfma_f32_16x16x16bf16_1k(bits4(a), bits4(b), c, 0, 0, 0);
}

__device__ __forceinline__ void async_load16(const void* g, void* l) {
    __builtin_amdgcn_global_load_lds(
        (__attribute__((address_space(1))) void*)g,
        (__attribute__((address_space(3))) void*)l,
        16, 0, 0);
}

// ---- merged prep: convert x -> bf16 | transpose w_attn | transpose w_proj --
#define NCONV (MTOT * DMODEL / 4 / 256)            // 8192 blocks
#define NWAT  ((NQKV / 64) * (DMODEL / 64))        // 768
#define NWPT  ((DMODEL / 64) * (DMODEL / 64))      // 256

__device__ __forceinline__ void transpose_tile(
    const float* __restrict__ in, u16* __restrict__ out, int R, int C,
    int bx, int by, int tid)
{
    __shared__ float tile[64][65];
    int r0 = by * 64, c0 = bx * 64;
    #pragma unroll
    for (int i = 0; i < 16; ++i) {
        int idx = tid + i * 256;
        int r = idx >> 6, c = idx & 63;
        tile[r][c] = in[(size_t)(r0 + r) * C + c0 + c];
    }
    __syncthreads();
    #pragma unroll
    for (int i = 0; i < 16; ++i) {
        int idx = tid + i * 256;
        int c = idx >> 6, r = idx & 63;
        out[(size_t)(c0 + c) * R + r0 + r] = f2bf(tile[r][c]);
    }
}

__global__ void prep_kernel(
    const float4* __restrict__ x4, ushort4* __restrict__ xb4,
    const float* __restrict__ w_attn, u16* __restrict__ wat,
    const float* __restrict__ w_proj, u16* __restrict__ wpt)
{
    const int bid = blockIdx.x;
    const int tid = threadIdx.x;
    if (bid < NCONV) {
        int i = bid * 256 + tid;
        float4 f = x4[i];
        ushort4 o;
        o.x = f2bf(f.x); o.y = f2bf(f.y); o.z = f2bf(f.z); o.w = f2bf(f.w);
        xb4[i] = o;
    } else if (bid < NCONV + NWAT) {
        int b2 = bid - NCONV;
        transpose_tile(w_attn, wat, DMODEL, NQKV, b2 % (NQKV / 64), b2 / (NQKV / 64), tid);
    } else {
        int b3 = bid - NCONV - NWAT;
        transpose_tile(w_proj, wpt, DMODEL, DMODEL, b3 % (DMODEL / 64), b3 / (DMODEL / 64), tid);
    }
}

// ---- GEMM16Q: C = A @ Bt^T + bias, 4 quadrant phases (R12 structure) -------
// BM=256, BN=NF*64, BK=64; 8 waves (wm=wave>>2 M, wn=wave&3 N); per-wave
// 128 x NF*16 (mf 0..7, nf 0..NF-1, 16x16x32 MFMA). LDS: A 4 half-slots
// [par][half] 128x64; B 2 slots [par] BNx64. Chunk-XOR swizzle both-sides
// (0 conflicts verified). Phase p: {af reads m-frags 2p,2p+1 (+ all bfr in
// p0) | stage 1 half-tile | BAR | setprio+MFMA(disjoint acc)+setprio | BAR}.
// Staging: p0/p1 A(t+1) halves; p2/p3 B(t+2) into live parity (safe: bfr
// retired by p0 MFMA + 2 barriers). Boundary: counted vmcnt, never 0 in-loop.
// OUTMODE 0: fp32 C stride N (proj). OUTMODE 1: QKV split — QK blocks ->
// bf16 qk stride 2048; V blocks (n0>=2048, block-uniform) -> LDS-transposed
// 128B-coalesced stores into vt[bh][d][s].
// Mapping: xcd=bid&7 owns fixed 4-mb-row A panel (2MB L2-resident), sweeps nb.
template<int NF, int OUTMODE>
__global__ __launch_bounds__(512, 2) void gemm16q(
    const u16* __restrict__ A, const u16* __restrict__ Bt,
    const float* __restrict__ bias, void* __restrict__ C,
    u16* __restrict__ vt, int M, int N, int K)
{
    constexpr int NBH = NF / 2;            // B half-tiles per K-tile (2 or 1)
    constexpr int BSLOT = NF * 4096;       // u16 per B parity buffer
    __shared__ __attribute__((aligned(16))) u16 sm[32768 + 2 * BSLOT];
    u16* const As = sm;                    // 4 x 8192: slot (par*2+half)
    u16* const Bs = sm + 32768;            // 2 x BSLOT: slot par

    const int tid = threadIdx.x;
    const int wave = tid >> 6, lane = tid & 63;
    const int l15 = lane & 15, q4 = lane >> 4;
    const int wm = wave >> 2, wn = wave & 3;

    const int bid = (int)blockIdx.x;
    const int xcd = bid & 7;
    const int lx  = bid >> 3;
    const int MB  = M >> 8;                // 32
    const int PM  = MB >> 3;               // 4
    const int nb  = lx / PM;
    const int mb  = xcd * PM + (lx - nb * PM);
    const int m0 = mb << 8, n0 = nb * NF * 64;

    const u16* Ag = A + (size_t)m0 * K;
    const u16* Bg = Bt + (size_t)n0 * K;

    const int srow = tid >> 3;
    const size_t goff0 = (size_t)srow * K + (size_t)(((tid & 7) ^ (srow & 7)) * 8);
    const size_t goff1 = goff0 + (size_t)64 * K;
    const int ldso = tid * 8;

    const int ck0 = (q4 ^ (l15 & 7)) * 8;
    const int ck1 = ((4 + q4) ^ (l15 & 7)) * 8;
    const int rb0 = (wn * NF * 16 + l15) * 64;   // B row base (nf=0)

    f32x4 acc[8][NF] = {};
    const int T = K >> 6;

#define STAGE_A(t_, h_) do { \
    const u16* ga_ = Ag + (size_t)(h_) * 128 * K + (size_t)(t_) * 64; \
    u16* da_ = As + (((t_) & 1) * 2 + (h_)) * 8192; \
    async_load16(ga_ + goff0, da_ + ldso); \
    async_load16(ga_ + goff1, da_ + ldso + 4096); \
} while (0)

#define STAGE_B(t_, h_) do { \
    const u16* gb_ = Bg + (size_t)(h_) * 128 * K + (size_t)(t_) * 64; \
    u16* db_ = Bs + ((t_) & 1) * BSLOT + (h_) * 8192; \
    async_load16(gb_ + goff0, db_ + ldso); \
    async_load16(gb_ + goff1, db_ + ldso + 4096); \
} while (0)

#define LOAD_AF(P_) do { \
    af[0][0] = *(const bf16x8*)(Ah + ((2 * (P_)) * 16 + l15) * 64 + ck0); \
    af[0][1] = *(const bf16x8*)(Ah + ((2 * (P_)) * 16 + l15) * 64 + ck1); \
    af[1][0] = *(const bf16x8*)(Ah + ((2 * (P_) + 1) * 16 + l15) * 64 + ck0); \
    af[1][1] = *(const bf16x8*)(Ah + ((2 * (P_) + 1) * 16 + l15) * 64 + ck1); \
} while (0)

#define PHASE_MFMA(P_) do { \
    __builtin_amdgcn_s_barrier(); \
    __builtin_amdgcn_s_setprio(1); \
    _Pragma("unroll") \
    for (int i_ = 0; i_ < 2; ++i_) \
        _Pragma("unroll") \
        for (int nf_ = 0; nf_ < NF; ++nf_) \
            _Pragma("unroll") \
            for (int kk_ = 0; kk_ < 2; ++kk_) \
                acc[2 * (P_) + i_][nf_] = __builtin_amdgcn_mfma_f32_16x16x32_bf16( \
                    af[i_][kk_], bfr[nf_][kk_], acc[2 * (P_) + i_][nf_], 0, 0, 0); \
    __builtin_amdgcn_s_setprio(0); \
} while (0)

    // prologue: A(0) both halves + B(0) + B(1); keep B(1) in flight
    STAGE_A(0, 0); STAGE_A(0, 1);
    STAGE_B(0, 0); if constexpr (NBH == 2) STAGE_B(0, 1);
    if (T > 1) {
        STAGE_B(1, 0); if constexpr (NBH == 2) STAGE_B(1, 1);
        if constexpr (NBH == 2) asm volatile("s_waitcnt vmcnt(4)");
        else                    asm volatile("s_waitcnt vmcnt(2)");
    } else {
        asm volatile("s_waitcnt vmcnt(0)");
    }
    __builtin_amdgcn_sched_barrier(0);
    __builtin_amdgcn_s_barrier();

    for (int t = 0; t < T; ++t) {
        const int par = t & 1;
        const u16* Ah = As + (par * 2 + wm) * 8192;   // this wave's A half
        const u16* Bl = Bs + par * BSLOT;

        bf16x8 af[2][2], bfr[NF][2];

        // ---- phase 0: ALL bfr (held all tile) + af m-frags 0,1;
        //               stage A(t+1).h0 --------------------------------------
        #pragma unroll
        for (int nf = 0; nf < NF; ++nf) {
            bfr[nf][0] = *(const bf16x8*)(Bl + rb0 + nf * (16 * 64) + ck0);
            bfr[nf][1] = *(const bf16x8*)(Bl + rb0 + nf * (16 * 64) + ck1);
        }
        LOAD_AF(0);
        if (t + 1 < T) STAGE_A(t + 1, 0);
        PHASE_MFMA(0);
        __builtin_amdgcn_s_barrier();

        // ---- phase 1: af m-frags 2,3; stage A(t+1).h1 ----------------------
        LOAD_AF(1);
        if (t + 1 < T) STAGE_A(t + 1, 1);
        PHASE_MFMA(1);
        __builtin_amdgcn_s_barrier();

        // ---- phase 2: af m-frags 4,5; stage B(t+2).h0 into B[par] ----------
        LOAD_AF(2);
        if (t + 2 < T) STAGE_B(t + 2, 0);
        PHASE_MFMA(2);
        __builtin_amdgcn_s_barrier();

        // ---- phase 3: af m-frags 6,7; stage B(t+2).h1 ----------------------
        LOAD_AF(3);
        if constexpr (NBH == 2) { if (t + 2 < T) STAGE_B(t + 2, 1); }
        PHASE_MFMA(3);
        // boundary: A(t+1)+B(t+1) complete; B(t+2) loads stay in flight
        if (t + 1 < T) {
            if (t + 2 < T) {
                if constexpr (NBH == 2) asm volatile("s_waitcnt vmcnt(4)");
                else                    asm volatile("s_waitcnt vmcnt(2)");
            } else {
                asm volatile("s_waitcnt vmcnt(0)");
            }
            __builtin_amdgcn_sched_barrier(0);
            __builtin_amdgcn_s_barrier();
        }
    }

#undef STAGE_A
#undef STAGE_B
#undef LOAD_AF
#undef PHASE_MFMA

    // ---- V-block epilogue (OUTMODE 1, n0 >= 2048, block-uniform): ----------
    // stage 256s x 256d bf16 tile (128KB, exactly sm) through LDS, then
    // 128B-coalesced stores into vt[bh][d][s]. Granule = 4 u16 (8B);
    // LDS pos of (d', s-granule g) = (d'*64 + (g ^ (d'&63))) * 4 u16.
    if constexpr (OUTMODE == 1) {
        if (n0 >= 2 * DMODEL && NF == 4) {
            __syncthreads();             // all K-loop LDS reads done
            #pragma unroll
            for (int mf = 0; mf < 8; ++mf) {
                #pragma unroll
                for (int nf = 0; nf < NF; ++nf) {
                    const int dp = wn * NF * 16 + nf * 16 + l15;   // 0..255
                    const float bv = bias[n0 + dp];
                    const int g = wm * 32 + mf * 4 + q4;           // s-granule
                    union { __bf16 b[4]; uint2 v; } pk;
                    #pragma unroll
                    for (int r = 0; r < 4; ++r)
                        pk.b[r] = (__bf16)(acc[mf][nf][r] + bv);
                    *(uint2*)&sm[(dp * 64 + (g ^ (dp & 63))) * 4] = pk.v;
                }
            }
            __syncthreads();
            const int b_  = m0 >> 11;
            const int s0  = m0 & (S_LEN - 1);
            const int dv0 = n0 - 2 * DMODEL;
            #pragma unroll
            for (int j = 0; j < 8; ++j) {
                const int dp = wave * 32 + (lane >> 4) + j * 4;    // 0..255
                const int dglob = dv0 + dp;
                const int bh = b_ * NHEAD + (dglob >> 6);
                const int dd = dglob & 63;
                u16* dst = vt + ((size_t)bh * 64 + dd) * S_LEN + s0;
                #pragma unroll
                for (int k = 0; k < 4; ++k) {
                    const int g = l15 + 16 * k;                    // 0..63
                    uint2 v = *(const uint2*)&sm[(dp * 64 + (g ^ (dp & 63))) * 4];
                    *(uint2*)&dst[g * 4] = v;   // 16 lanes x 8B contiguous
                }
            }
            return;
        }
    }

    // ---- normal epilogue: C/D col=l15, row=q4*4+r (QK blocks / proj) -------
    #pragma unroll
    for (int mf = 0; mf < 8; ++mf) {
        const int row = m0 + wm * 128 + mf * 16 + q4 * 4;
        #pragma unroll
        for (int nf = 0; nf < NF; ++nf) {
            const int col = n0 + wn * NF * 16 + nf * 16 + l15;
            const float bv = bias[col];
            if constexpr (OUTMODE == 0) {
                #pragma unroll
                for (int r = 0; r < 4; ++r)
                    ((float*)C)[(size_t)(row + r) * N + col] = acc[mf][nf][r] + bv;
            } else {
                #pragma unroll
                for (int r = 0; r < 4; ++r)
                    ((u16*)C)[(size_t)(row + r) * QKN + col] = f2bf(acc[mf][nf][r] + bv);
            }
        }
    }
}

// ---- flash attention R6 (Q/K read from dense qk, stride QKN) ---------------
__device__ __forceinline__ void stage_tiles(
    const u16* __restrict__ qk, const u16* __restrict__ vt,
    size_t base, int bh, int h, int w, int srow8, int schunk,
    int kt, u16* __restrict__ KsB, u16* __restrict__ VsB)
{
    #pragma unroll
    for (int q = 0; q < 2; ++q) {
        int rloc = w * 16 + q * 8 + srow8;
        int sc = ((schunk ^ (rloc & 7)) * 8);
        async_load16(qk + (base + (size_t)kt * 64 + rloc) * (size_t)QKN + DMODEL + h * HDIM + sc,
                     KsB + (w * 16 + q * 8) * 64);
        async_load16(vt + ((size_t)bh * 64 + rloc) * S_LEN + kt * 64 + sc,
                     VsB + (w * 16 + q * 8) * 64);
    }
}

__device__ __forceinline__ void attn_pass(
    int qt, const u16* __restrict__ qk, const u16* __restrict__ vt,
    __bf16* __restrict__ outb, u16 (*Ks)[64 * 64], u16 (*Vs)[64 * 64],
    int w, int lane, int bh, int h, size_t base)
{
    const int l15 = lane & 15, q4 = lane >> 4;
    const int srow8 = lane >> 3, schunk = lane & 7;

    // Q fragments for both halves ([n=q=l15][k=d=q4*8+j]); scale folds
    // 1/sqrt(64) * log2(e) so P = 2^(K·Q^T) == e^(K·Q^T/8).
    const float QSCALE = 0.125f * 1.44269504f;
    bf16x8 qf[2][2];
    #pragma unroll
    for (int mh = 0; mh < 2; ++mh) {
        int qrow = qt * 128 + mh * 64 + w * 16 + l15;
        #pragma unroll
        for (int kc = 0; kc < 2; ++kc) {
            bf16x8 raw = *(const bf16x8*)(qk + (base + qrow) * (size_t)QKN + h * HDIM + kc * 32 + q4 * 8);
            bf16x8 sc;
            #pragma unroll
            for (int j = 0; j < 8; ++j) sc[j] = (__bf16)((float)raw[j] * QSCALE);
            qf[mh][kc] = sc;
        }
    }

    bf16x4 ones4;
    #pragma unroll
    for (int j = 0; j < 4; ++j) ones4[j] = (__bf16)1.0f;

    f32x4 o0[4] = {}, o1[4] = {};   // O^T: [d-tile mt][q=l15], rows d=q4*4+r
    f32x4 la0 = {}, la1 = {};       // l[q=l15]

    const int ktlast = 2 * qt + 1;  // tail tile (half-0 fully masked)

    __syncthreads();                // protect LDS reuse across passes
    stage_tiles(qk, vt, base, bh, h, w, srow8, schunk, 0, Ks[0], Vs[0]);
    if (ktlast >= 1)
        stage_tiles(qk, vt, base, bh, h, w, srow8, schunk, 1, Ks[1], Vs[1]);

    for (int kt = 0; kt <= 2 * qt; ++kt) {
        const int buf = kt % 3;
        __syncthreads();            // kt,kt+1 staged; reads of buf (kt+2)%3 done
        int pf = kt + 2;
        if (pf <= ktlast)
            stage_tiles(qk, vt, base, bh, h, w, srow8, schunk, pf, Ks[pf % 3], Vs[pf % 3]);

        // S^T = K·Q^T; kf shared across halves
        f32x4 st0[4] = {}, st1[4] = {};
        #pragma unroll
        for (int nt = 0; nt < 4; ++nt) {
            int n = nt * 16 + l15;      // key row in Ks
            #pragma unroll
            for (int kc = 0; kc < 2; ++kc) {
                int ch = (((kc * 4 + q4) ^ (n & 7)) * 8);
                bf16x8 kf = *(const bf16x8*)(&Ks[buf][n * 64 + ch]);
                st0[nt] = __builtin_amdgcn_mfma_f32_16x16x32_bf16(kf, qf[0][kc], st0[nt], 0, 0, 0);
                st1[nt] = __builtin_amdgcn_mfma_f32_16x16x32_bf16(kf, qf[1][kc], st1[nt], 0, 0, 0);
            }
        }

        if (kt == 2 * qt) {             // diagonal for half 0 (uniform branch)
            #pragma unroll
            for (int nt = 0; nt < 4; ++nt)
                #pragma unroll
                for (int r = 0; r < 4; ++r) {
                    int keyl = nt * 16 + q4 * 4 + r;
                    if (keyl > w * 16 + l15) st0[nt][r] = -1e30f;
                }
        }

        // P^T = 2^(S^T) packed to bf16x4 B-frags (k = q4*4+j), in registers
        bf16x4 pb0[4], pb1[4];
        #pragma unroll
        for (int nt = 0; nt < 4; ++nt)
            #pragma unroll
            for (int r = 0; r < 4; ++r) {
                pb0[nt][r] = (__bf16)__builtin_amdgcn_exp2f(st0[nt][r]);
                pb1[nt][r] = (__bf16)__builtin_amdgcn_exp2f(st1[nt][r]);
            }

        // O^T += V^T · P^T  (vf shared across halves); l += ones · P^T
        #pragma unroll
        for (int nt = 0; nt < 4; ++nt) {
            #pragma unroll
            for (int mt = 0; mt < 4; ++mt) {
                int row = mt * 16 + l15;                       // d row in Vs
                int ch = (nt * 2 + (q4 >> 1)) ^ (row & 7);
                bf16x4 vf = *(const bf16x4*)(&Vs[buf][row * 64 + ch * 8 + (q4 & 1) * 4]);
                o0[mt] = mfma16(vf, pb0[nt], o0[mt]);
                o1[mt] = mfma16(vf, pb1[nt], o1[mt]);
            }
            la0 = mfma16(ones4, pb0[nt], la0);
            la1 = mfma16(ones4, pb1[nt], la1);
        }
    }

    // ---- tail tile ktlast: half 0 fully masked; half 1 only ----------------
    {
        const int buf = ktlast % 3;
        __syncthreads();

        f32x4 st1[4] = {};
        #pragma unroll
        for (int nt = 0; nt < 4; ++nt) {
            int n = nt * 16 + l15;
            #pragma unroll
            for (int kc = 0; kc < 2; ++kc) {
                int ch = (((kc * 4 + q4) ^ (n & 7)) * 8);
                bf16x8 kf = *(const bf16x8*)(&Ks[buf][n * 64 + ch]);
                st1[nt] = __builtin_amdgcn_mfma_f32_16x16x32_bf16(kf, qf[1][kc], st1[nt], 0, 0, 0);
            }
        }
        bf16x4 pb1[4];
        #pragma unroll
        for (int nt = 0; nt < 4; ++nt)
            #pragma unroll
            for (int r = 0; r < 4; ++r) {
                int keyl = nt * 16 + q4 * 4 + r;
                float s = (keyl > w * 16 + l15) ? -1e30f : st1[nt][r];
                pb1[nt][r] = (__bf16)__builtin_amdgcn_exp2f(s);
            }
        #pragma unroll
        for (int nt = 0; nt < 4; ++nt) {
            #pragma unroll
            for (int mt = 0; mt < 4; ++mt) {
                int row = mt * 16 + l15;
                int ch = (nt * 2 + (q4 >> 1)) ^ (row & 7);
                bf16x4 vf = *(const bf16x4*)(&Vs[buf][row * 64 + ch * 8 + (q4 & 1) * 4]);
                o1[mt] = mfma16(vf, pb1[nt], o1[mt]);
            }
            la1 = mfma16(ones4, pb1[nt], la1);
        }
    }

    // epilogue: lane holds O^T[d = mt*16+q4*4+r][q=l15]; packed 8B stores
    float inv0 = 1.0f / la0[0], inv1 = 1.0f / la1[0];
    int row0 = qt * 128 + w * 16 + l15;
    int row1 = row0 + 64;
    #pragma unroll
    for (int mt = 0; mt < 4; ++mt) {
        union { __bf16 b[4]; ushort4 v; } p0, p1;
        #pragma unroll
        for (int r = 0; r < 4; ++r) {
            p0.b[r] = (__bf16)(o0[mt][r] * inv0);
            p1.b[r] = (__bf16)(o1[mt][r] * inv1);
        }
        int col = h * HDIM + mt * 16 + q4 * 4;
        *(ushort4*)(&outb[(base + row0) * (size_t)DMODEL + col]) = p0.v;
        *(ushort4*)(&outb[(base + row1) * (size_t)DMODEL + col]) = p1.v;
    }
}

// block = (bx, bh): processes Q-tiles qt = NT-1-bx and qt = bx (34 K-iters
// total for every block -> perfect load balance). gridDim.x = NT/2 = 8.
__global__ __launch_bounds__(256, 3) void attn_kernel(
    const u16* __restrict__ qk, const u16* __restrict__ vt, u16* __restrict__ out)
{
    __shared__ __attribute__((aligned(16))) u16 Ks[3][64 * 64];
    __shared__ __attribute__((aligned(16))) u16 Vs[3][64 * 64];

    const int tid = threadIdx.x;
    const int w = tid >> 6, lane = tid & 63;
    const int bh = blockIdx.y;
    const int b = bh >> 4, h = bh & 15;
    const size_t base = (size_t)b * S_LEN;
    const int NT = (int)gridDim.x * 2;           // 16

    attn_pass(NT - 1 - (int)blockIdx.x, qk, vt, (__bf16*)out, Ks, Vs, w, lane, bh, h, base);
    attn_pass((int)blockIdx.x,          qk, vt, (__bf16*)out, Ks, Vs, w, lane, bh, h, base);
}

extern "C" void kernel_launch(void* const* d_in, const int* in_sizes, int n_in,
                              void* d_out, int out_size, void* d_ws, size_t ws_size,
                              hipStream_t stream) {
    const float* x      = (const float*)d_in[0];
    // d_in[1] = mask (causal tril) — implemented structurally, not read
    const float* w_attn = (const float*)d_in[2];
    const float* b_attn = (const float*)d_in[3];
    const float* w_proj = (const float*)d_in[4];
    const float* b_proj = (const float*)d_in[5];

    u16* xb   = (u16*)d_ws;                                   // 8192x1024
    u16* wat  = xb  + (size_t)MTOT * DMODEL;                  // 3072x1024
    u16* wpt  = wat + (size_t)NQKV * DMODEL;                  // 1024x1024
    u16* qk   = wpt + (size_t)DMODEL * DMODEL;                // 8192x2048 (Q|K dense)
    u16* vt   = qk  + (size_t)MTOT * QKN;                     // Vt[64 bh][64 d][2048 s]
    u16* attn = vt  + (size_t)64 * 64 * S_LEN;                // 8192x1024

    prep_kernel<<<NCONV + NWAT + NWPT, 256, 0, stream>>>(
        (const float4*)x, (ushort4*)xb, w_attn, wat, w_proj, wpt);

    gemm16q<4, 1><<<dim3((MTOT / 256) * (NQKV / 256)), 512, 0, stream>>>(
        xb, wat, b_attn, (void*)qk, vt, MTOT, NQKV, DMODEL);

    attn_kernel<<<dim3(S_LEN / 256, 4 * NHEAD), 256, 0, stream>>>(qk, vt, attn);

    gemm16q<2, 0><<<dim3((MTOT / 256) * (DMODEL / 128)), 512, 0, stream>>>(
        attn, wpt, b_proj, d_out, nullptr, MTOT, DMODEL, DMODEL);
}

// Round 13
// 255.580 us; speedup vs baseline: 1.3121x; 1.0008x over previous
//
#include <hip/hip_runtime.h>
#include <hip/hip_bf16.h>
#include <stdint.h>

// ---------------------------------------------------------------------------
// CausalSelfAttention: x(4,2048,1024) fp32 -> out fp32
// qkv = x@w_attn+b_attn; flash-attn causal (H=16,hd=64); out = attn@w_proj+b_proj
// R18b: resubmission of R18 (round-12 bench was an infra double-failure, no
//   signal). Kernel audited for hang/OOB sources: swizzle involution verified
//   both sides, all global writes in-bounds, LDS epilogue exactly 32KB,
//   (dp,g) coverage bijective, block-uniform epilogue branch, every LDS reuse
//   barrier-separated. No spin loops / cooperative launch.
// R18: GEMM back to the m97-verified 128x128/BK=32 multi-block structure.
//   All six 256^2 variants (R7-R17) hold 128KB LDS -> 1 block/CU -> barrier
//   stalls have nothing to overlap with (27% MfmaUtil plateau). The 128^2
//   tile (32KB LDS, 3 blocks/CU, plain 2-barrier loop) is HW-verified at
//   ~900TF via INTER-BLOCK overlap (m97/m103/m114). R0's gemm_bt was this
//   structure at 687TF, held back by 6.3M bank conflicts (linear [128][32]
//   LDS) + 58MB FETCH (PANEL map). Transplanted fixes (both verified in the
//   256^2 kernel): chunk-XOR swizzle on the [64][8-chunk] view (staging src
//   inverse-permuted ch=(lane&7)^(lane>>3); frag reads rp*64+(ch^rp&7)*8 —
//   2-lanes-per-bank = free) and XCD A-panel mapping (xcd owns 8 mb tiles =
//   2MB L2-resident, sweeps nb). R17 OUTMODE epilogues kept: Q|K -> dense qk
//   (stride 2048); V-blocks -> 32KB-LDS transpose -> 128B-coalesced vt.
//   Grids: QKV 1536 (6 block-waves/CU), proj 512 (2/CU - overlap at last).
// attn (R6, ~67us): paired Q-tiles, triple-buffered K/V ring. prep merged.
// Workspace: xb 16MB | wat 6MB | wpt 2MB | qk 32MB | vt 16MB | attn 16MB = 88MB
// ---------------------------------------------------------------------------

typedef uint16_t u16;
typedef __bf16 bf16x8 __attribute__((ext_vector_type(8)));
typedef __bf16 bf16x4 __attribute__((ext_vector_type(4)));
typedef short s16x4 __attribute__((ext_vector_type(4)));
typedef float f32x4 __attribute__((ext_vector_type(4)));

#define S_LEN 2048
#define DMODEL 1024
#define NHEAD 16
#define HDIM 64
#define MTOT 8192   // B*S
#define NQKV 3072
#define QKN 2048    // dense Q|K row stride after fused split

__device__ __forceinline__ u16 f2bf(float f) {
    union { float f; uint32_t u; } v; v.f = f;
    uint32_t u = v.u;
    return (u16)((u + 0x7fffu + ((u >> 16) & 1u)) >> 16);  // RNE
}

__device__ __forceinline__ s16x4 bits4(bf16x4 v) {
    union { bf16x4 b; s16x4 s; } u; u.b = v; return u.s;
}

// D = A*B + C, 16x16x16 bf16 (A,B: 4 bf16/lane, k = q4*4+j)
__device__ __forceinline__ f32x4 mfma16(bf16x4 a, bf16x4 b, f32x4 c) {
    return __builtin_amdgcn_mfma_f32_16x16x16bf16_1k(bits4(a), bits4(b), c, 0, 0, 0);
}

__device__ __forceinline__ void async_load16(const void* g, void* l) {
    __builtin_amdgcn_global_load_lds(
        (__attribute__((address_space(1))) void*)g,
        (__attribute__((address_space(3))) void*)l,
        16, 0, 0);
}

// ---- merged prep: convert x -> bf16 | transpose w_attn | transpose w_proj --
#define NCONV (MTOT * DMODEL / 4 / 256)            // 8192 blocks
#define NWAT  ((NQKV / 64) * (DMODEL / 64))        // 768
#define NWPT  ((DMODEL / 64) * (DMODEL / 64))      // 256

__device__ __forceinline__ void transpose_tile(
    const float* __restrict__ in, u16* __restrict__ out, int R, int C,
    int bx, int by, int tid)
{
    __shared__ float tile[64][65];
    int r0 = by * 64, c0 = bx * 64;
    #pragma unroll
    for (int i = 0; i < 16; ++i) {
        int idx = tid + i * 256;
        int r = idx >> 6, c = idx & 63;
        tile[r][c] = in[(size_t)(r0 + r) * C + c0 + c];
    }
    __syncthreads();
    #pragma unroll
    for (int i = 0; i < 16; ++i) {
        int idx = tid + i * 256;
        int c = idx >> 6, r = idx & 63;
        out[(size_t)(c0 + c) * R + r0 + r] = f2bf(tile[r][c]);
    }
}

__global__ void prep_kernel(
    const float4* __restrict__ x4, ushort4* __restrict__ xb4,
    const float* __restrict__ w_attn, u16* __restrict__ wat,
    const float* __restrict__ w_proj, u16* __restrict__ wpt)
{
    const int bid = blockIdx.x;
    const int tid = threadIdx.x;
    if (bid < NCONV) {
        int i = bid * 256 + tid;
        float4 f = x4[i];
        ushort4 o;
        o.x = f2bf(f.x); o.y = f2bf(f.y); o.z = f2bf(f.z); o.w = f2bf(f.w);
        xb4[i] = o;
    } else if (bid < NCONV + NWAT) {
        int b2 = bid - NCONV;
        transpose_tile(w_attn, wat, DMODEL, NQKV, b2 % (NQKV / 64), b2 / (NQKV / 64), tid);
    } else {
        int b3 = bid - NCONV - NWAT;
        transpose_tile(w_proj, wpt, DMODEL, DMODEL, b3 % (DMODEL / 64), b3 / (DMODEL / 64), tid);
    }
}

// ---- GEMM_BT: C[M,N] = A[M,K] @ Bt[N,K]^T + bias ---------------------------
// 128x128 tile, BK=32, 256 threads (2x2 waves, 64x64/wave, 16x16x32 MFMA).
// Plain 2-barrier loop: stage(global_load_lds w16) -> sync -> frags+16 MFMA
// -> sync. 32KB LDS (main loop 16KB) -> 3 blocks/CU: inter-block overlap
// covers barrier stalls (m97/m114 mechanism — no explicit pipelining).
// LDS swizzle: tile viewed as [64 lines][8 chunks of 16B]; chunk ch of line
// rp stored at slot ch^(rp&7). Staging keeps LINEAR dest (wave-uniform base,
// HW lane x 16B) and inverse-permutes the SOURCE: lane covers slot
// (rp=base+lane>>3, p=lane&7) -> src chunk ch=p^(lane>>3) -> row 2rp+(ch>>2),
// col (ch&3)*8. Frag reads at rp*64+(ch^(rp&7))*8: every bank-quad gets
// exactly 2 lanes = conflict-free (same pattern as the verified 256^2 one).
// Mapping: xcd=bid&7 owns 8 fixed mb tiles (2MB A panel, L2-resident),
// sweeps nb. OUTMODE 0: fp32 C stride N (proj). OUTMODE 1: nb<16 -> bf16 qk
// stride 2048; nb>=16 (V, block-uniform) -> 32KB LDS transpose -> vt.
template<int OUTMODE>
__global__ __launch_bounds__(256, 3) void gemm_bt(
    const u16* __restrict__ A, const u16* __restrict__ Bt,
    const float* __restrict__ bias, void* __restrict__ C,
    u16* __restrict__ vt, int M, int N, int K)
{
    __shared__ __attribute__((aligned(16))) u16 sm[16384];   // 32KB
    u16* const As = sm;            // 4096 u16 (128x32)
    u16* const Bs = sm + 4096;     // 4096 u16

    const int tid = threadIdx.x;
    const int wave = tid >> 6, lane = tid & 63;
    const int l15 = lane & 15, q4 = lane >> 4;
    const int wm = wave >> 1, wn = wave & 1;

    // XCD-resident A-panel mapping
    const int bid = (int)blockIdx.x;
    const int xcd = bid & 7;
    const int lx  = bid >> 3;
    const int nb  = lx >> 3;               // lx / 8
    const int mb  = xcd * 8 + (lx & 7);
    const int m0 = mb << 7, n0 = nb << 7;

    const u16* Ag = A + (size_t)m0 * K;
    const u16* Bg = Bt + (size_t)n0 * K;

    // staging source (inverse swizzle): lane covers slot (rp_base+lane>>3, lane&7)
    const int l3 = lane >> 3;
    const int sch = (lane & 7) ^ l3;                   // source chunk in line
    const int srow = wave * 32 + 2 * l3 + (sch >> 2);  // + q*16 per shot
    const int scol = (sch & 3) * 8;
    const int ldst = (wave * 32) * 32;                 // + q*512 per shot (u16)

    // frag read offsets (u16): off(t) = w*2048 + t*512 + ck
    const int ck = (l15 >> 1) * 64 + ((((l15 & 1) * 4 + q4) ^ (l15 >> 1)) * 8);

    f32x4 acc[4][4] = {};

    for (int k0 = 0; k0 < K; k0 += 32) {
        #pragma unroll
        for (int q = 0; q < 2; ++q) {
            async_load16(Ag + (size_t)(srow + q * 16) * K + k0 + scol, As + ldst + q * 512);
            async_load16(Bg + (size_t)(srow + q * 16) * K + k0 + scol, Bs + ldst + q * 512);
        }
        __syncthreads();

        bf16x8 af[4], bfr[4];
        #pragma unroll
        for (int t = 0; t < 4; ++t) {
            af[t]  = *(const bf16x8*)(As + wm * 2048 + t * 512 + ck);
            bfr[t] = *(const bf16x8*)(Bs + wn * 2048 + t * 512 + ck);
        }
        #pragma unroll
        for (int tm = 0; tm < 4; ++tm)
            #pragma unroll
            for (int tn = 0; tn < 4; ++tn)
                acc[tm][tn] = __builtin_amdgcn_mfma_f32_16x16x32_bf16(af[tm], bfr[tn], acc[tm][tn], 0, 0, 0);
        __syncthreads();
    }

    // ---- V-block epilogue (OUTMODE 1, nb >= 16, block-uniform) -------------
    // 128 s x 128 d bf16 tile through 32KB LDS: [dp 0..127][granule g 0..31]
    // at (dp*32 + (g ^ (dp&31)))*4 u16; then 128B-coalesced stores into vt.
    if constexpr (OUTMODE == 1) {
        if (n0 >= 2 * DMODEL) {
            #pragma unroll
            for (int tm = 0; tm < 4; ++tm) {
                const int g = wm * 16 + tm * 4 + q4;           // s-granule
                #pragma unroll
                for (int tn = 0; tn < 4; ++tn) {
                    const int dp = wn * 64 + tn * 16 + l15;    // 0..127
                    const float bv = bias[n0 + dp];
                    union { __bf16 b[4]; uint2 v; } pk;
                    #pragma unroll
                    for (int r = 0; r < 4; ++r)
                        pk.b[r] = (__bf16)(acc[tm][tn][r] + bv);
                    *(uint2*)&sm[(dp * 32 + (g ^ (dp & 31))) * 4] = pk.v;
                }
            }
            __syncthreads();
            const int b_  = m0 >> 11;
            const int s0  = m0 & (S_LEN - 1);
            const int dv0 = n0 - 2 * DMODEL;
            #pragma unroll
            for (int j = 0; j < 8; ++j) {
                const int dp = wave * 32 + q4 * 8 + j;         // 0..127
                const int dglob = dv0 + dp;
                const int bh = b_ * NHEAD + (dglob >> 6);
                const int dd = dglob & 63;
                u16* dst = vt + ((size_t)bh * 64 + dd) * S_LEN + s0;
                #pragma unroll
                for (int k = 0; k < 2; ++k) {
                    const int g = l15 + 16 * k;                // 0..31
                    uint2 v = *(const uint2*)&sm[(dp * 32 + (g ^ (dp & 31))) * 4];
                    *(uint2*)&dst[g * 4] = v;   // 16 lanes x 8B contiguous
                }
            }
            return;
        }
    }

    // ---- normal epilogue: C/D col=l15, row=q4*4+r (QK blocks / proj) -------
    #pragma unroll
    for (int tm = 0; tm < 4; ++tm) {
        const int row = m0 + wm * 64 + tm * 16 + q4 * 4;
        #pragma unroll
        for (int tn = 0; tn < 4; ++tn) {
            const int col = n0 + wn * 64 + tn * 16 + l15;
            const float bv = bias[col];
            if constexpr (OUTMODE == 0) {
                #pragma unroll
                for (int r = 0; r < 4; ++r)
                    ((float*)C)[(size_t)(row + r) * N + col] = acc[tm][tn][r] + bv;
            } else {
                #pragma unroll
                for (int r = 0; r < 4; ++r)
                    ((u16*)C)[(size_t)(row + r) * QKN + col] = f2bf(acc[tm][tn][r] + bv);
            }
        }
    }
}

// ---- flash attention R6 (Q/K read from dense qk, stride QKN) ---------------
__device__ __forceinline__ void stage_tiles(
    const u16* __restrict__ qk, const u16* __restrict__ vt,
    size_t base, int bh, int h, int w, int srow8, int schunk,
    int kt, u16* __restrict__ KsB, u16* __restrict__ VsB)
{
    #pragma unroll
    for (int q = 0; q < 2; ++q) {
        int rloc = w * 16 + q * 8 + srow8;
        int sc = ((schunk ^ (rloc & 7)) * 8);
        async_load16(qk + (base + (size_t)kt * 64 + rloc) * (size_t)QKN + DMODEL + h * HDIM + sc,
                     KsB + (w * 16 + q * 8) * 64);
        async_load16(vt + ((size_t)bh * 64 + rloc) * S_LEN + kt * 64 + sc,
                     VsB + (w * 16 + q * 8) * 64);
    }
}

__device__ __forceinline__ void attn_pass(
    int qt, const u16* __restrict__ qk, const u16* __restrict__ vt,
    __bf16* __restrict__ outb, u16 (*Ks)[64 * 64], u16 (*Vs)[64 * 64],
    int w, int lane, int bh, int h, size_t base)
{
    const int l15 = lane & 15, q4 = lane >> 4;
    const int srow8 = lane >> 3, schunk = lane & 7;

    // Q fragments for both halves ([n=q=l15][k=d=q4*8+j]); scale folds
    // 1/sqrt(64) * log2(e) so P = 2^(K·Q^T) == e^(K·Q^T/8).
    const float QSCALE = 0.125f * 1.44269504f;
    bf16x8 qf[2][2];
    #pragma unroll
    for (int mh = 0; mh < 2; ++mh) {
        int qrow = qt * 128 + mh * 64 + w * 16 + l15;
        #pragma unroll
        for (int kc = 0; kc < 2; ++kc) {
            bf16x8 raw = *(const bf16x8*)(qk + (base + qrow) * (size_t)QKN + h * HDIM + kc * 32 + q4 * 8);
            bf16x8 sc;
            #pragma unroll
            for (int j = 0; j < 8; ++j) sc[j] = (__bf16)((float)raw[j] * QSCALE);
            qf[mh][kc] = sc;
        }
    }

    bf16x4 ones4;
    #pragma unroll
    for (int j = 0; j < 4; ++j) ones4[j] = (__bf16)1.0f;

    f32x4 o0[4] = {}, o1[4] = {};   // O^T: [d-tile mt][q=l15], rows d=q4*4+r
    f32x4 la0 = {}, la1 = {};       // l[q=l15]

    const int ktlast = 2 * qt + 1;  // tail tile (half-0 fully masked)

    __syncthreads();                // protect LDS reuse across passes
    stage_tiles(qk, vt, base, bh, h, w, srow8, schunk, 0, Ks[0], Vs[0]);
    if (ktlast >= 1)
        stage_tiles(qk, vt, base, bh, h, w, srow8, schunk, 1, Ks[1], Vs[1]);

    for (int kt = 0; kt <= 2 * qt; ++kt) {
        const int buf = kt % 3;
        __syncthreads();            // kt,kt+1 staged; reads of buf (kt+2)%3 done
        int pf = kt + 2;
        if (pf <= ktlast)
            stage_tiles(qk, vt, base, bh, h, w, srow8, schunk, pf, Ks[pf % 3], Vs[pf % 3]);

        // S^T = K·Q^T; kf shared across halves
        f32x4 st0[4] = {}, st1[4] = {};
        #pragma unroll
        for (int nt = 0; nt < 4; ++nt) {
            int n = nt * 16 + l15;      // key row in Ks
            #pragma unroll
            for (int kc = 0; kc < 2; ++kc) {
                int ch = (((kc * 4 + q4) ^ (n & 7)) * 8);
                bf16x8 kf = *(const bf16x8*)(&Ks[buf][n * 64 + ch]);
                st0[nt] = __builtin_amdgcn_mfma_f32_16x16x32_bf16(kf, qf[0][kc], st0[nt], 0, 0, 0);
                st1[nt] = __builtin_amdgcn_mfma_f32_16x16x32_bf16(kf, qf[1][kc], st1[nt], 0, 0, 0);
            }
        }

        if (kt == 2 * qt) {             // diagonal for half 0 (uniform branch)
            #pragma unroll
            for (int nt = 0; nt < 4; ++nt)
                #pragma unroll
                for (int r = 0; r < 4; ++r) {
                    int keyl = nt * 16 + q4 * 4 + r;
                    if (keyl > w * 16 + l15) st0[nt][r] = -1e30f;
                }
        }

        // P^T = 2^(S^T) packed to bf16x4 B-frags (k = q4*4+j), in registers
        bf16x4 pb0[4], pb1[4];
        #pragma unroll
        for (int nt = 0; nt < 4; ++nt)
            #pragma unroll
            for (int r = 0; r < 4; ++r) {
                pb0[nt][r] = (__bf16)__builtin_amdgcn_exp2f(st0[nt][r]);
                pb1[nt][r] = (__bf16)__builtin_amdgcn_exp2f(st1[nt][r]);
            }

        // O^T += V^T · P^T  (vf shared across halves); l += ones · P^T
        #pragma unroll
        for (int nt = 0; nt < 4; ++nt) {
            #pragma unroll
            for (int mt = 0; mt < 4; ++mt) {
                int row = mt * 16 + l15;                       // d row in Vs
                int ch = (nt * 2 + (q4 >> 1)) ^ (row & 7);
                bf16x4 vf = *(const bf16x4*)(&Vs[buf][row * 64 + ch * 8 + (q4 & 1) * 4]);
                o0[mt] = mfma16(vf, pb0[nt], o0[mt]);
                o1[mt] = mfma16(vf, pb1[nt], o1[mt]);
            }
            la0 = mfma16(ones4, pb0[nt], la0);
            la1 = mfma16(ones4, pb1[nt], la1);
        }
    }

    // ---- tail tile ktlast: half 0 fully masked; half 1 only ----------------
    {
        const int buf = ktlast % 3;
        __syncthreads();

        f32x4 st1[4] = {};
        #pragma unroll
        for (int nt = 0; nt < 4; ++nt) {
            int n = nt * 16 + l15;
            #pragma unroll
            for (int kc = 0; kc < 2; ++kc) {
                int ch = (((kc * 4 + q4) ^ (n & 7)) * 8);
                bf16x8 kf = *(const bf16x8*)(&Ks[buf][n * 64 + ch]);
                st1[nt] = __builtin_amdgcn_mfma_f32_16x16x32_bf16(kf, qf[1][kc], st1[nt], 0, 0, 0);
            }
        }
        bf16x4 pb1[4];
        #pragma unroll
        for (int nt = 0; nt < 4; ++nt)
            #pragma unroll
            for (int r = 0; r < 4; ++r) {
                int keyl = nt * 16 + q4 * 4 + r;
                float s = (keyl > w * 16 + l15) ? -1e30f : st1[nt][r];
                pb1[nt][r] = (__bf16)__builtin_amdgcn_exp2f(s);
            }
        #pragma unroll
        for (int nt = 0; nt < 4; ++nt) {
            #pragma unroll
            for (int mt = 0; mt < 4; ++mt) {
                int row = mt * 16 + l15;
                int ch = (nt * 2 + (q4 >> 1)) ^ (row & 7);
                bf16x4 vf = *(const bf16x4*)(&Vs[buf][row * 64 + ch * 8 + (q4 & 1) * 4]);
                o1[mt] = mfma16(vf, pb1[nt], o1[mt]);
            }
            la1 = mfma16(ones4, pb1[nt], la1);
        }
    }

    // epilogue: lane holds O^T[d = mt*16+q4*4+r][q=l15]; packed 8B stores
    float inv0 = 1.0f / la0[0], inv1 = 1.0f / la1[0];
    int row0 = qt * 128 + w * 16 + l15;
    int row1 = row0 + 64;
    #pragma unroll
    for (int mt = 0; mt < 4; ++mt) {
        union { __bf16 b[4]; ushort4 v; } p0, p1;
        #pragma unroll
        for (int r = 0; r < 4; ++r) {
            p0.b[r] = (__bf16)(o0[mt][r] * inv0);
            p1.b[r] = (__bf16)(o1[mt][r] * inv1);
        }
        int col = h * HDIM + mt * 16 + q4 * 4;
        *(ushort4*)(&outb[(base + row0) * (size_t)DMODEL + col]) = p0.v;
        *(ushort4*)(&outb[(base + row1) * (size_t)DMODEL + col]) = p1.v;
    }
}

// block = (bx, bh): processes Q-tiles qt = NT-1-bx and qt = bx (34 K-iters
// total for every block -> perfect load balance). gridDim.x = NT/2 = 8.
__global__ __launch_bounds__(256, 3) void attn_kernel(
    const u16* __restrict__ qk, const u16* __restrict__ vt, u16* __restrict__ out)
{
    __shared__ __attribute__((aligned(16))) u16 Ks[3][64 * 64];
    __shared__ __attribute__((aligned(16))) u16 Vs[3][64 * 64];

    const int tid = threadIdx.x;
    const int w = tid >> 6, lane = tid & 63;
    const int bh = blockIdx.y;
    const int b = bh >> 4, h = bh & 15;
    const size_t base = (size_t)b * S_LEN;
    const int NT = (int)gridDim.x * 2;           // 16

    attn_pass(NT - 1 - (int)blockIdx.x, qk, vt, (__bf16*)out, Ks, Vs, w, lane, bh, h, base);
    attn_pass((int)blockIdx.x,          qk, vt, (__bf16*)out, Ks, Vs, w, lane, bh, h, base);
}

extern "C" void kernel_launch(void* const* d_in, const int* in_sizes, int n_in,
                              void* d_out, int out_size, void* d_ws, size_t ws_size,
                              hipStream_t stream) {
    const float* x      = (const float*)d_in[0];
    // d_in[1] = mask (causal tril) — implemented structurally, not read
    const float* w_attn = (const float*)d_in[2];
    const float* b_attn = (const float*)d_in[3];
    const float* w_proj = (const float*)d_in[4];
    const float* b_proj = (const float*)d_in[5];

    u16* xb   = (u16*)d_ws;                                   // 8192x1024
    u16* wat  = xb  + (size_t)MTOT * DMODEL;                  // 3072x1024
    u16* wpt  = wat + (size_t)NQKV * DMODEL;                  // 1024x1024
    u16* qk   = wpt + (size_t)DMODEL * DMODEL;                // 8192x2048 (Q|K dense)
    u16* vt   = qk  + (size_t)MTOT * QKN;                     // Vt[64 bh][64 d][2048 s]
    u16* attn = vt  + (size_t)64 * 64 * S_LEN;                // 8192x1024

    prep_kernel<<<NCONV + NWAT + NWPT, 256, 0, stream>>>(
        (const float4*)x, (ushort4*)xb, w_attn, wat, w_proj, wpt);

    gemm_bt<1><<<dim3((MTOT / 128) * (NQKV / 128)), 256, 0, stream>>>(
        xb, wat, b_attn, (void*)qk, vt, MTOT, NQKV, DMODEL);

    attn_kernel<<<dim3(S_LEN / 256, 4 * NHEAD), 256, 0, stream>>>(qk, vt, attn);

    gemm_bt<0><<<dim3((MTOT / 128) * (DMODEL / 128)), 256, 0, stream>>>(
        attn, wpt, b_proj, d_out, nullptr, MTOT, DMODEL, DMODEL);
}